// Round 1
// baseline (21077.972 us; speedup 1.0000x reference)
//
#include <hip/hip_runtime.h>
#include <cmath>

#define MAXV 8

// ---------------------------------------------------------------------------
// Kernel 1: cost matrix. One thread per (b, m, n) over padded [B, M, M].
// Mirrors the reference's f32 math: rotated corners, Sutherland-Hodgman clip
// of pred quad by target quad (keep-left, den clamp 1e-9), shoelace area,
// union, axis-aligned enclosing box, giou cost, plus score cost.
// ---------------------------------------------------------------------------
__global__ __launch_bounds__(256) void cost_kernel(
    const float* __restrict__ p_box, const float* __restrict__ p_score,
    const float* __restrict__ t_box, const float* __restrict__ t_score,
    float* __restrict__ cost, float* __restrict__ boxc,
    int B, int M, int N)
{
    int g = blockIdx.x * 256 + threadIdx.x;
    int total = B * M * M;
    if (g >= total) return;
    int b = g / (M * M);
    int rem = g - b * M * M;
    int m = rem / M;
    int n = rem - m * M;

    if (n >= N) { cost[g] = 0.0f; return; }  // zero-padded columns

    const float* bp = p_box + ((size_t)b * M + m) * 5;
    const float* bt = t_box + ((size_t)b * N + n) * 5;
    float pcx = bp[0], pcy = bp[1], pw = bp[2], ph = bp[3], pth = bp[4];
    float tcx = bt[0], tcy = bt[1], tw = bt[2], th = bt[3], tth = bt[4];

    float pc = cosf(pth), ps = sinf(pth);
    float tc = cosf(tth), ts = sinf(tth);

    const float DX[4] = {-0.5f, 0.5f, 0.5f, -0.5f};
    const float DY[4] = {-0.5f, -0.5f, 0.5f, 0.5f};
    float cpx[4], cpy[4], ctx[4], cty[4];
#pragma unroll
    for (int k = 0; k < 4; k++) {
        float dx = DX[k] * pw, dy = DY[k] * ph;
        cpx[k] = pcx + dx * pc - dy * ps;
        cpy[k] = pcy + dx * ps + dy * pc;
        float dx2 = DX[k] * tw, dy2 = DY[k] * th;
        ctx[k] = tcx + dx2 * tc - dy2 * ts;
        cty[k] = tcy + dx2 * ts + dy2 * tc;
    }

    // subject polygon = pred corners
    float px[MAXV], py[MAXV];
#pragma unroll
    for (int k = 0; k < MAXV; k++) {
        px[k] = (k < 4) ? cpx[k] : 0.0f;
        py[k] = (k < 4) ? cpy[k] : 0.0f;
    }
    int cnt = 4;

#pragma unroll
    for (int e = 0; e < 4; e++) {
        float ax = ctx[e], ay = cty[e];
        float bx2 = ctx[(e + 1) & 3], by2 = cty[(e + 1) & 3];
        float dx = bx2 - ax, dy = by2 - ay;
        float qx[MAXV], qy[MAXV];
#pragma unroll
        for (int k = 0; k < MAXV; k++) { qx[k] = 0.0f; qy[k] = 0.0f; }
        int nc = 0;
#pragma unroll
        for (int i = 0; i < MAXV; i++) {
            if (i < cnt) {
                bool wrap = !(i + 1 < cnt);
                float nx = wrap ? px[0] : px[(i + 1) & 7];
                float ny = wrap ? py[0] : py[(i + 1) & 7];
                float sc = dx * (py[i] - ay) - dy * (px[i] - ax);
                float sn = dx * (ny - ay) - dy * (nx - ax);
                bool inc = (sc >= 0.0f), inn = (sn >= 0.0f);
                float den = sc - sn;
                if (!(fabsf(den) > 1e-9f)) den = 1e-9f;
                float t = sc / den;
                float ix = px[i] + t * (nx - px[i]);
                float iy = py[i] + t * (ny - py[i]);
                if (inc) {
                    if (nc < MAXV) { qx[nc] = px[i]; qy[nc] = py[i]; }
                    nc++;
                }
                if (inc != inn) {
                    if (nc < MAXV) { qx[nc] = ix; qy[nc] = iy; }
                    nc++;
                }
            }
        }
        cnt = (nc > MAXV) ? MAXV : nc;
#pragma unroll
        for (int k = 0; k < MAXV; k++) {
            px[k] = (k < cnt) ? qx[k] : 0.0f;
            py[k] = (k < cnt) ? qy[k] : 0.0f;
        }
    }

    // shoelace
    float a2 = 0.0f;
#pragma unroll
    for (int i = 0; i < MAXV; i++) {
        if (i < cnt) {
            bool wrap = !(i + 1 < cnt);
            float nx = wrap ? px[0] : px[(i + 1) & 7];
            float ny = wrap ? py[0] : py[(i + 1) & 7];
            a2 += px[i] * ny - nx * py[i];
        }
    }
    float inter = 0.5f * fabsf(a2);

    float uni = tw * th + pw * ph - inter;

    float xmin = ctx[0], xmax = ctx[0], ymin = cty[0], ymax = cty[0];
#pragma unroll
    for (int k = 1; k < 4; k++) {
        xmin = fminf(xmin, ctx[k]); xmax = fmaxf(xmax, ctx[k]);
        ymin = fminf(ymin, cty[k]); ymax = fmaxf(ymax, cty[k]);
    }
#pragma unroll
    for (int k = 0; k < 4; k++) {
        xmin = fminf(xmin, cpx[k]); xmax = fmaxf(xmax, cpx[k]);
        ymin = fminf(ymin, cpy[k]); ymax = fmaxf(ymax, cpy[k]);
    }
    float enc = (xmax - xmin) * (ymax - ymin);

    float giou = inter / uni - (enc - uni) / enc;
    float bc = 1.0f - giou;
    float scst = fmaxf(0.0f, t_score[b * N + n] - p_score[b * M + m]);

    cost[g] = scst + bc;
    boxc[((size_t)b * M + m) * N + n] = bc;
}

// ---------------------------------------------------------------------------
// Kernel 2: exact JV Hungarian (float64, matching numpy _lsa) + matched sums.
// One 256-thread block per batch. Thread tid owns column j = tid+1:
// minv/v/used in registers; u/p/way in LDS. Argmin tie-break = smallest j
// (matches np.argmin first-minimum semantics).
// ---------------------------------------------------------------------------
__global__ __launch_bounds__(256) void hungarian_kernel(
    const float* __restrict__ cost, const float* __restrict__ boxc,
    const float* __restrict__ p_score, const float* __restrict__ t_score,
    float* __restrict__ out, int B, int M, int N)
{
    const double DINF = 1e30;
    int b = blockIdx.x;
    int tid = threadIdx.x;
    const float* C = cost + (size_t)b * M * M;

    __shared__ double u[257];
    __shared__ int p[257];
    __shared__ int way[257];
    __shared__ double red_val[4];
    __shared__ int red_idx[4];
    __shared__ int sh_j0;
    __shared__ double sh_delta;

    int j = tid + 1;           // owned column, 1..M
    bool own = (j <= M);
    double v_r = 0.0;

    for (int k = tid; k <= M; k += 256) { u[k] = 0.0; p[k] = 0; way[k] = 0; }
    __syncthreads();

    for (int i = 1; i <= M; i++) {
        if (tid == 0) { p[0] = i; sh_j0 = 0; }
        double minv_r = DINF;
        int used_r = 0;
        __syncthreads();

        while (true) {
            int j0 = sh_j0;
            if (own && j == j0) used_r = 1;
            int i0 = p[j0];
            double ui0 = u[i0];
            const float* row = C + (size_t)(i0 - 1) * M;

            double val = DINF;
            if (own && !used_r) {
                double cur = ((double)row[j - 1] - ui0) - v_r;
                if (cur < minv_r) { minv_r = cur; way[j] = j0; }
                val = minv_r;
            }

            // (val, idx) min-reduction, smallest index on ties
            int idx = j;
            for (int off = 32; off > 0; off >>= 1) {
                double v2 = __shfl_down(val, off, 64);
                int i2 = __shfl_down(idx, off, 64);
                if (v2 < val || (v2 == val && i2 < idx)) { val = v2; idx = i2; }
            }
            if ((tid & 63) == 0) { red_val[tid >> 6] = val; red_idx[tid >> 6] = idx; }
            __syncthreads();
            if (tid == 0) {
                double bv = red_val[0]; int bi = red_idx[0];
                for (int w = 1; w < 4; w++) {
                    double v2 = red_val[w]; int i2 = red_idx[w];
                    if (v2 < bv || (v2 == bv && i2 < bi)) { bv = v2; bi = i2; }
                }
                sh_delta = bv; sh_j0 = bi;
            }
            __syncthreads();

            double delta = sh_delta;
            int jn = sh_j0;
            if (own && used_r) {
                u[p[j]] += delta;   // distinct rows per used column -> race-free
                v_r -= delta;
            } else if (own) {
                minv_r -= delta;
            }
            if (tid == 0) u[p[0]] += delta;  // the j0=0 virtual column
            __syncthreads();

            if (p[jn] == 0) break;
        }

        // augment along way[] (thread 0, serial)
        if (tid == 0) {
            int j0 = sh_j0;
            while (j0 != 0) { int j1 = way[j0]; p[j0] = p[j1]; j0 = j1; }
        }
        __syncthreads();
    }

    // matched sums: column j -> row p[j]
    double sm = 0.0, ss = 0.0, sb = 0.0;
    if (own) {
        int r = p[j] - 1, c = j - 1;
        sm = (double)C[(size_t)r * M + c];
        if (c < N) {
            sb = (double)boxc[((size_t)b * M + r) * N + c];
            float scf = fmaxf(0.0f, t_score[b * N + c] - p_score[b * M + r]);
            ss = (double)scf;
        }
    }
    for (int off = 32; off > 0; off >>= 1) {
        sm += __shfl_down(sm, off, 64);
        ss += __shfl_down(ss, off, 64);
        sb += __shfl_down(sb, off, 64);
    }
    __shared__ double rs[3][4];
    if ((tid & 63) == 0) { int w = tid >> 6; rs[0][w] = sm; rs[1][w] = ss; rs[2][w] = sb; }
    __syncthreads();
    if (tid == 0) {
        double m0 = 0, s0 = 0, b0 = 0;
        for (int w = 0; w < 4; w++) { m0 += rs[0][w]; s0 += rs[1][w]; b0 += rs[2][w]; }
        out[0 * B + b] = (float)(m0 / N);
        out[1 * B + b] = (float)(s0 / N);
        out[2 * B + b] = (float)(b0 / N);
    }
}

extern "C" void kernel_launch(void* const* d_in, const int* in_sizes, int n_in,
                              void* d_out, int out_size, void* d_ws, size_t ws_size,
                              hipStream_t stream) {
    int B = out_size / 3;                 // out is [3, B]
    int M = in_sizes[1] / B;              // pred_score [B, M]
    int N = in_sizes[3] / B;              // target_score [B, N]

    const float* p_box   = (const float*)d_in[0];
    const float* p_score = (const float*)d_in[1];
    const float* t_box   = (const float*)d_in[2];
    const float* t_score = (const float*)d_in[3];
    float* out = (float*)d_out;

    float* cost = (float*)d_ws;                       // [B, M, M]
    float* boxc = cost + (size_t)B * M * M;           // [B, M, N]

    int total = B * M * M;
    cost_kernel<<<(total + 255) / 256, 256, 0, stream>>>(
        p_box, p_score, t_box, t_score, cost, boxc, B, M, N);
    hungarian_kernel<<<B, 256, 0, stream>>>(
        cost, boxc, p_score, t_score, out, B, M, N);
}

// Round 2
// 16222.490 us; speedup vs baseline: 1.2993x; 1.2993x over previous
//
#include <hip/hip_runtime.h>
#include <cmath>

#define MAXV 8

// ---------------------------------------------------------------------------
// Kernel 1: cost matrix. One thread per (b, m, n) over padded [B, M, M].
// Mirrors the reference's f32 math exactly.
// ---------------------------------------------------------------------------
__global__ __launch_bounds__(256) void cost_kernel(
    const float* __restrict__ p_box, const float* __restrict__ p_score,
    const float* __restrict__ t_box, const float* __restrict__ t_score,
    float* __restrict__ cost, float* __restrict__ boxc,
    int B, int M, int N)
{
    int g = blockIdx.x * 256 + threadIdx.x;
    int total = B * M * M;
    if (g >= total) return;
    int b = g / (M * M);
    int rem = g - b * M * M;
    int m = rem / M;
    int n = rem - m * M;

    if (n >= N) { cost[g] = 0.0f; return; }  // zero-padded columns

    const float* bp = p_box + ((size_t)b * M + m) * 5;
    const float* bt = t_box + ((size_t)b * N + n) * 5;
    float pcx = bp[0], pcy = bp[1], pw = bp[2], ph = bp[3], pth = bp[4];
    float tcx = bt[0], tcy = bt[1], tw = bt[2], th = bt[3], tth = bt[4];

    float pc = cosf(pth), ps = sinf(pth);
    float tc = cosf(tth), ts = sinf(tth);

    const float DX[4] = {-0.5f, 0.5f, 0.5f, -0.5f};
    const float DY[4] = {-0.5f, -0.5f, 0.5f, 0.5f};
    float cpx[4], cpy[4], ctx[4], cty[4];
#pragma unroll
    for (int k = 0; k < 4; k++) {
        float dx = DX[k] * pw, dy = DY[k] * ph;
        cpx[k] = pcx + dx * pc - dy * ps;
        cpy[k] = pcy + dx * ps + dy * pc;
        float dx2 = DX[k] * tw, dy2 = DY[k] * th;
        ctx[k] = tcx + dx2 * tc - dy2 * ts;
        cty[k] = tcy + dx2 * ts + dy2 * tc;
    }

    float px[MAXV], py[MAXV];
#pragma unroll
    for (int k = 0; k < MAXV; k++) {
        px[k] = (k < 4) ? cpx[k] : 0.0f;
        py[k] = (k < 4) ? cpy[k] : 0.0f;
    }
    int cnt = 4;

#pragma unroll
    for (int e = 0; e < 4; e++) {
        float ax = ctx[e], ay = cty[e];
        float bx2 = ctx[(e + 1) & 3], by2 = cty[(e + 1) & 3];
        float dx = bx2 - ax, dy = by2 - ay;
        float qx[MAXV], qy[MAXV];
#pragma unroll
        for (int k = 0; k < MAXV; k++) { qx[k] = 0.0f; qy[k] = 0.0f; }
        int nc = 0;
#pragma unroll
        for (int i = 0; i < MAXV; i++) {
            if (i < cnt) {
                bool wrap = !(i + 1 < cnt);
                float nx = wrap ? px[0] : px[(i + 1) & 7];
                float ny = wrap ? py[0] : py[(i + 1) & 7];
                float sc = dx * (py[i] - ay) - dy * (px[i] - ax);
                float sn = dx * (ny - ay) - dy * (nx - ax);
                bool inc = (sc >= 0.0f), inn = (sn >= 0.0f);
                float den = sc - sn;
                if (!(fabsf(den) > 1e-9f)) den = 1e-9f;
                float t = sc / den;
                float ix = px[i] + t * (nx - px[i]);
                float iy = py[i] + t * (ny - py[i]);
                if (inc) {
                    if (nc < MAXV) { qx[nc] = px[i]; qy[nc] = py[i]; }
                    nc++;
                }
                if (inc != inn) {
                    if (nc < MAXV) { qx[nc] = ix; qy[nc] = iy; }
                    nc++;
                }
            }
        }
        cnt = (nc > MAXV) ? MAXV : nc;
#pragma unroll
        for (int k = 0; k < MAXV; k++) {
            px[k] = (k < cnt) ? qx[k] : 0.0f;
            py[k] = (k < cnt) ? qy[k] : 0.0f;
        }
    }

    float a2 = 0.0f;
#pragma unroll
    for (int i = 0; i < MAXV; i++) {
        if (i < cnt) {
            bool wrap = !(i + 1 < cnt);
            float nx = wrap ? px[0] : px[(i + 1) & 7];
            float ny = wrap ? py[0] : py[(i + 1) & 7];
            a2 += px[i] * ny - nx * py[i];
        }
    }
    float inter = 0.5f * fabsf(a2);

    float uni = tw * th + pw * ph - inter;

    float xmin = ctx[0], xmax = ctx[0], ymin = cty[0], ymax = cty[0];
#pragma unroll
    for (int k = 1; k < 4; k++) {
        xmin = fminf(xmin, ctx[k]); xmax = fmaxf(xmax, ctx[k]);
        ymin = fminf(ymin, cty[k]); ymax = fmaxf(ymax, cty[k]);
    }
#pragma unroll
    for (int k = 0; k < 4; k++) {
        xmin = fminf(xmin, cpx[k]); xmax = fmaxf(xmax, cpx[k]);
        ymin = fminf(ymin, cpy[k]); ymax = fmaxf(ymax, cpy[k]);
    }
    float enc = (xmax - xmin) * (ymax - ymin);

    float giou = inter / uni - (enc - uni) / enc;
    float bc = 1.0f - giou;
    float scst = fmaxf(0.0f, t_score[b * N + n] - p_score[b * M + m]);

    cost[g] = scst + bc;
    boxc[((size_t)b * M + m) * N + n] = bc;
}

// ---------------------------------------------------------------------------
// Kernel 2: exact JV Hungarian (float64, numpy _lsa op order), single wave
// per batch, barrier-free. Lane l owns columns 4l+1 .. 4l+4 (1-based).
// minv/v/way/p in registers; u[257] in LDS. Argmin = 6-step shfl_xor
// butterfly on monotonic u64 key + lowest-lane ballot (== np.argmin
// first-minimum tie-break, since columns are lane-ordered).
// ---------------------------------------------------------------------------
__device__ __forceinline__ unsigned long long d2key(double d) {
    unsigned long long b = (unsigned long long)__double_as_longlong(d);
    unsigned long long mask =
        (unsigned long long)(((long long)b) >> 63) | 0x8000000000000000ULL;
    return b ^ mask;   // monotonic: a<b (double) <=> key(a)<key(b) (u64)
}
__device__ __forceinline__ double key2d(unsigned long long k) {
    unsigned long long b = (k >> 63) ? (k ^ 0x8000000000000000ULL) : ~k;
    return __longlong_as_double((long long)b);
}
__device__ __forceinline__ int sel4(int a0, int a1, int a2, int a3, int s) {
    return s == 0 ? a0 : (s == 1 ? a1 : (s == 2 ? a2 : a3));
}

__global__ __launch_bounds__(64) void hungarian_wave(
    const float* __restrict__ cost, const float* __restrict__ boxc,
    const float* __restrict__ p_score, const float* __restrict__ t_score,
    float* __restrict__ out, int B, int M, int N)
{
    const double DINF = 1e30;
    const unsigned long long KINF = d2key(1e30);
    int b = blockIdx.x;
    int lane = threadIdx.x;
    const float* C = cost + (size_t)b * M * M;

    __shared__ double u[257];
    for (int k = lane; k <= M; k += 64) u[k] = 0.0;
    __syncthreads();

    const int j_base = 4 * lane + 1;      // first owned column (1-based)
    double v0 = 0.0, v1 = 0.0, v2 = 0.0, v3 = 0.0;
    double m0, m1, m2, m3;
    int p0 = 0, p1 = 0, p2 = 0, p3 = 0;
    int w0 = 0, w1 = 0, w2 = 0, w3 = 0;

    for (int i = 1; i <= M; ++i) {
        m0 = DINF; m1 = DINF; m2 = DINF; m3 = DINF;
        int usedm = 0;
        int j0 = 0;          // wave-uniform current column (0 = virtual)
        int i0 = i;          // p[j0]; p[0] == i for this phase
        int jn;

        while (true) {
            // used[j0] = True
            if (j0 != 0 && ((j0 - 1) >> 2) == lane) usedm |= 1 << ((j0 - 1) & 3);

            double u0 = u[i0];
            const float4 r4 = *reinterpret_cast<const float4*>(
                C + (size_t)(i0 - 1) * M + 4 * lane);

            // cur = (c - u) - v ; strict < update of minv/way (free cols only)
            unsigned long long k0 = KINF, k1 = KINF, k2 = KINF, k3 = KINF;
            if (!(usedm & 1)) {
                double cur = ((double)r4.x - u0) - v0;
                if (cur < m0) { m0 = cur; w0 = j0; }
                k0 = d2key(m0);
            }
            if (!(usedm & 2)) {
                double cur = ((double)r4.y - u0) - v1;
                if (cur < m1) { m1 = cur; w1 = j0; }
                k1 = d2key(m1);
            }
            if (!(usedm & 4)) {
                double cur = ((double)r4.z - u0) - v2;
                if (cur < m2) { m2 = cur; w2 = j0; }
                k2 = d2key(m2);
            }
            if (!(usedm & 8)) {
                double cur = ((double)r4.w - u0) - v3;
                if (cur < m3) { m3 = cur; w3 = j0; }
                k3 = d2key(m3);
            }

            // lane-local (min, smallest j) over 4 slots
            unsigned long long ka = k0; int sa = 0;
            if (k1 < ka) { ka = k1; sa = 1; }
            if (k2 < ka) { ka = k2; sa = 2; }
            if (k3 < ka) { ka = k3; sa = 3; }
            int ja = j_base + sa;
            int pa = sel4(p0, p1, p2, p3, sa);   // p of my candidate column

            // wave min (value only) via xor butterfly
            unsigned long long km = ka;
#pragma unroll
            for (int off = 1; off < 64; off <<= 1) {
                unsigned long long ko = __shfl_xor(km, off, 64);
                km = (ko < km) ? ko : km;
            }
            double delta = key2d(km);
            unsigned long long ball = __ballot(ka == km);
            int owner = __builtin_ctzll(ball);   // lowest lane = smallest j
            jn = __shfl(ja, owner, 64);
            int pjn = __shfl(pa, owner, 64);

            // u[p[used]] += delta ; v[used] -= delta ; minv[free] -= delta
            if (usedm & 1) { u[p0] += delta; v0 -= delta; } else m0 -= delta;
            if (usedm & 2) { u[p1] += delta; v1 -= delta; } else m1 -= delta;
            if (usedm & 4) { u[p2] += delta; v2 -= delta; } else m2 -= delta;
            if (usedm & 8) { u[p3] += delta; v3 -= delta; } else m3 -= delta;
            if (lane == 0) u[i] += delta;        // virtual column 0: p[0] = i

            if (pjn == 0) break;
            j0 = jn; i0 = pjn;
        }

        // augment: while j0 != 0: j1 = way[j0]; p[j0] = p[j1]; j0 = j1
        int jj = jn;
        while (jj != 0) {
            int s = (jj - 1) & 3, o = (jj - 1) >> 2;
            int wv = sel4(w0, w1, w2, w3, s);
            int j1 = __shfl(wv, o, 64);
            int pn;
            if (j1 == 0) pn = i;
            else {
                int s1 = (j1 - 1) & 3, o1 = (j1 - 1) >> 2;
                int pv = sel4(p0, p1, p2, p3, s1);
                pn = __shfl(pv, o1, 64);
            }
            if (o == lane) {
                if (s == 0) p0 = pn;
                else if (s == 1) p1 = pn;
                else if (s == 2) p2 = pn;
                else p3 = pn;
            }
            jj = j1;
        }
    }

    // matched sums: column j (owned) -> row p[j]
    double sm = 0.0, ss = 0.0, sb = 0.0;
#pragma unroll
    for (int s = 0; s < 4; ++s) {
        int j = j_base + s;
        int r = sel4(p0, p1, p2, p3, s);
        int c = j - 1;
        sm += (double)C[(size_t)(r - 1) * M + c];
        if (c < N) {
            sb += (double)boxc[((size_t)b * M + (r - 1)) * N + c];
            ss += (double)fmaxf(0.0f, t_score[b * N + c] - p_score[b * M + (r - 1)]);
        }
    }
#pragma unroll
    for (int off = 1; off < 64; off <<= 1) {
        sm += __shfl_xor(sm, off, 64);
        ss += __shfl_xor(ss, off, 64);
        sb += __shfl_xor(sb, off, 64);
    }
    if (lane == 0) {
        out[0 * B + b] = (float)(sm / N);
        out[1 * B + b] = (float)(ss / N);
        out[2 * B + b] = (float)(sb / N);
    }
}

extern "C" void kernel_launch(void* const* d_in, const int* in_sizes, int n_in,
                              void* d_out, int out_size, void* d_ws, size_t ws_size,
                              hipStream_t stream) {
    int B = out_size / 3;                 // out is [3, B]
    int M = in_sizes[1] / B;              // pred_score [B, M]
    int N = in_sizes[3] / B;              // target_score [B, N]

    const float* p_box   = (const float*)d_in[0];
    const float* p_score = (const float*)d_in[1];
    const float* t_box   = (const float*)d_in[2];
    const float* t_score = (const float*)d_in[3];
    float* out = (float*)d_out;

    float* cost = (float*)d_ws;                       // [B, M, M]
    float* boxc = cost + (size_t)B * M * M;           // [B, M, N]

    int total = B * M * M;
    cost_kernel<<<(total + 255) / 256, 256, 0, stream>>>(
        p_box, p_score, t_box, t_score, cost, boxc, B, M, N);
    hungarian_wave<<<B, 64, 0, stream>>>(
        cost, boxc, p_score, t_score, out, B, M, N);
}

// Round 3
// 1260.914 us; speedup vs baseline: 16.7164x; 12.8657x over previous
//
#include <hip/hip_runtime.h>
#include <cmath>

#define MAXV 8

// ---------------------------------------------------------------------------
// Kernel 1: cost matrices for the RECTANGULAR problem (no padding).
// One thread per (b, n, m), m fastest. Writes:
//   Ct[b][n][m]  = score_cost + giou_cost   (transposed cost, coalesced rows)
//   boxc[b][m][n] = giou_cost
// Math mirrors the reference f32 op order exactly.
// ---------------------------------------------------------------------------
__global__ __launch_bounds__(256) void cost_kernel(
    const float* __restrict__ p_box, const float* __restrict__ p_score,
    const float* __restrict__ t_box, const float* __restrict__ t_score,
    float* __restrict__ Ct, float* __restrict__ boxc,
    int B, int M, int N)
{
    int g = blockIdx.x * 256 + threadIdx.x;
    int total = B * M * N;
    if (g >= total) return;
    int b = g / (M * N);
    int rem = g - b * M * N;
    int n = rem / M;
    int m = rem - n * M;

    const float* bp = p_box + ((size_t)b * M + m) * 5;
    const float* bt = t_box + ((size_t)b * N + n) * 5;
    float pcx = bp[0], pcy = bp[1], pw = bp[2], ph = bp[3], pth = bp[4];
    float tcx = bt[0], tcy = bt[1], tw = bt[2], th = bt[3], tth = bt[4];

    float pc = cosf(pth), ps = sinf(pth);
    float tc = cosf(tth), ts = sinf(tth);

    const float DX[4] = {-0.5f, 0.5f, 0.5f, -0.5f};
    const float DY[4] = {-0.5f, -0.5f, 0.5f, 0.5f};
    float cpx[4], cpy[4], ctx[4], cty[4];
#pragma unroll
    for (int k = 0; k < 4; k++) {
        float dx = DX[k] * pw, dy = DY[k] * ph;
        cpx[k] = pcx + dx * pc - dy * ps;
        cpy[k] = pcy + dx * ps + dy * pc;
        float dx2 = DX[k] * tw, dy2 = DY[k] * th;
        ctx[k] = tcx + dx2 * tc - dy2 * ts;
        cty[k] = tcy + dx2 * ts + dy2 * tc;
    }

    float px[MAXV], py[MAXV];
#pragma unroll
    for (int k = 0; k < MAXV; k++) {
        px[k] = (k < 4) ? cpx[k] : 0.0f;
        py[k] = (k < 4) ? cpy[k] : 0.0f;
    }
    int cnt = 4;

#pragma unroll
    for (int e = 0; e < 4; e++) {
        float ax = ctx[e], ay = cty[e];
        float bx2 = ctx[(e + 1) & 3], by2 = cty[(e + 1) & 3];
        float dx = bx2 - ax, dy = by2 - ay;
        float qx[MAXV], qy[MAXV];
#pragma unroll
        for (int k = 0; k < MAXV; k++) { qx[k] = 0.0f; qy[k] = 0.0f; }
        int nc = 0;
#pragma unroll
        for (int i = 0; i < MAXV; i++) {
            if (i < cnt) {
                bool wrap = !(i + 1 < cnt);
                float nx = wrap ? px[0] : px[(i + 1) & 7];
                float ny = wrap ? py[0] : py[(i + 1) & 7];
                float sc = dx * (py[i] - ay) - dy * (px[i] - ax);
                float sn = dx * (ny - ay) - dy * (nx - ax);
                bool inc = (sc >= 0.0f), inn = (sn >= 0.0f);
                float den = sc - sn;
                if (!(fabsf(den) > 1e-9f)) den = 1e-9f;
                float t = sc / den;
                float ix = px[i] + t * (nx - px[i]);
                float iy = py[i] + t * (ny - py[i]);
                if (inc) {
                    if (nc < MAXV) { qx[nc] = px[i]; qy[nc] = py[i]; }
                    nc++;
                }
                if (inc != inn) {
                    if (nc < MAXV) { qx[nc] = ix; qy[nc] = iy; }
                    nc++;
                }
            }
        }
        cnt = (nc > MAXV) ? MAXV : nc;
#pragma unroll
        for (int k = 0; k < MAXV; k++) {
            px[k] = (k < cnt) ? qx[k] : 0.0f;
            py[k] = (k < cnt) ? qy[k] : 0.0f;
        }
    }

    float a2 = 0.0f;
#pragma unroll
    for (int i = 0; i < MAXV; i++) {
        if (i < cnt) {
            bool wrap = !(i + 1 < cnt);
            float nx = wrap ? px[0] : px[(i + 1) & 7];
            float ny = wrap ? py[0] : py[(i + 1) & 7];
            a2 += px[i] * ny - nx * py[i];
        }
    }
    float inter = 0.5f * fabsf(a2);

    float uni = tw * th + pw * ph - inter;

    float xmin = ctx[0], xmax = ctx[0], ymin = cty[0], ymax = cty[0];
#pragma unroll
    for (int k = 1; k < 4; k++) {
        xmin = fminf(xmin, ctx[k]); xmax = fmaxf(xmax, ctx[k]);
        ymin = fminf(ymin, cty[k]); ymax = fmaxf(ymax, cty[k]);
    }
#pragma unroll
    for (int k = 0; k < 4; k++) {
        xmin = fminf(xmin, cpx[k]); xmax = fmaxf(xmax, cpx[k]);
        ymin = fminf(ymin, cpy[k]); ymax = fmaxf(ymax, cpy[k]);
    }
    float enc = (xmax - xmin) * (ymax - ymin);

    float giou = inter / uni - (enc - uni) / enc;
    float bc = 1.0f - giou;
    float scst = fmaxf(0.0f, t_score[b * N + n] - p_score[b * M + m]);

    Ct[((size_t)b * N + n) * M + m] = scst + bc;
    boxc[((size_t)b * M + m) * N + n] = bc;
}

// ---------------------------------------------------------------------------
// Kernel 2: rectangular JV Hungarian on the transposed problem:
// N=192 phases (targets), 256 pred-columns. Single wave per batch,
// barrier-free. Lane l owns pred-columns 4l+1..4l+4 (1-based).
// u[targets] in LDS; v/minv/way/p in registers. The optimum is unique for
// continuous random costs, so this matching == numpy's square-padded
// matching restricted to real columns (padded cols contribute 0 to all
// three outputs). Early u/row reads for the next iteration are issued
// BEFORE this iteration's u writes (provably disjoint addresses) to
// overlap LDS/L2 latency with the update tail.
// ---------------------------------------------------------------------------
__device__ __forceinline__ unsigned long long d2key(double d) {
    unsigned long long b = (unsigned long long)__double_as_longlong(d);
    unsigned long long mask =
        (unsigned long long)(((long long)b) >> 63) | 0x8000000000000000ULL;
    return b ^ mask;   // monotonic: a<b (double) <=> key(a)<key(b) (u64)
}
__device__ __forceinline__ double key2d(unsigned long long k) {
    unsigned long long b = (k >> 63) ? (k ^ 0x8000000000000000ULL) : ~k;
    return __longlong_as_double((long long)b);
}
__device__ __forceinline__ int sel4(int a0, int a1, int a2, int a3, int s) {
    return s == 0 ? a0 : (s == 1 ? a1 : (s == 2 ? a2 : a3));
}

__global__ __launch_bounds__(64) void hungarian_rect(
    const float* __restrict__ Ct, const float* __restrict__ boxc,
    const float* __restrict__ p_score, const float* __restrict__ t_score,
    float* __restrict__ out, int B, int M, int N)
{
    const double DINF = 1e30;
    const unsigned long long KINF = d2key(1e30);
    int b = blockIdx.x;
    int lane = threadIdx.x;
    const float* C = Ct + (size_t)b * N * M;   // [N][M] rows contiguous

    __shared__ double u[256];                  // indexed by target 1..N
    for (int k = lane; k < 256; k += 64) u[k] = 0.0;
    __syncthreads();

    const int j_base = 4 * lane + 1;           // first owned pred-col (1-based)
    double v0 = 0.0, v1 = 0.0, v2 = 0.0, v3 = 0.0;
    double m0, m1, m2, m3;
    int p0 = 0, p1 = 0, p2 = 0, p3 = 0;        // pred-col -> matched target
    int w0 = 0, w1 = 0, w2 = 0, w3 = 0;

    for (int t = 1; t <= N; ++t) {
        m0 = DINF; m1 = DINF; m2 = DINF; m3 = DINF;
        int usedm = 0;
        int j0 = 0;                 // current pred-col (0 = virtual)
        double u0 = u[t];
        float4 r4 = *reinterpret_cast<const float4*>(
            C + (size_t)(t - 1) * M + 4 * lane);
        int jn, pjn;

        while (true) {
            if (j0 != 0 && ((j0 - 1) >> 2) == lane) usedm |= 1 << ((j0 - 1) & 3);

            // cur = (c - u) - v ; strict < update (free cols only)
            unsigned long long k0 = KINF, k1 = KINF, k2 = KINF, k3 = KINF;
            if (!(usedm & 1)) {
                double cur = ((double)r4.x - u0) - v0;
                if (cur < m0) { m0 = cur; w0 = j0; }
                k0 = d2key(m0);
            }
            if (!(usedm & 2)) {
                double cur = ((double)r4.y - u0) - v1;
                if (cur < m1) { m1 = cur; w1 = j0; }
                k1 = d2key(m1);
            }
            if (!(usedm & 4)) {
                double cur = ((double)r4.z - u0) - v2;
                if (cur < m2) { m2 = cur; w2 = j0; }
                k2 = d2key(m2);
            }
            if (!(usedm & 8)) {
                double cur = ((double)r4.w - u0) - v3;
                if (cur < m3) { m3 = cur; w3 = j0; }
                k3 = d2key(m3);
            }

            // lane-local (min, smallest j)
            unsigned long long ka = k0; int sa = 0;
            if (k1 < ka) { ka = k1; sa = 1; }
            if (k2 < ka) { ka = k2; sa = 2; }
            if (k3 < ka) { ka = k3; sa = 3; }
            int ja = j_base + sa;
            int pa = sel4(p0, p1, p2, p3, sa);

            // wave min via xor butterfly, then lowest-lane ballot
            unsigned long long km = ka;
#pragma unroll
            for (int off = 1; off < 64; off <<= 1) {
                unsigned long long ko = __shfl_xor(km, off, 64);
                km = (ko < km) ? ko : km;
            }
            unsigned long long ball = __ballot(ka == km);
            int owner = __builtin_ctzll(ball);
            jn = __shfl(ja, owner, 64);
            pjn = __shfl(pa, owner, 64);

            // ---- early reads for next iteration (addresses provably
            // untouched by this iteration's u writes) ----
            int nxt = (pjn > 0) ? pjn : 1;
            double u_next = u[nxt];
            float4 r4n = *reinterpret_cast<const float4*>(
                C + (size_t)(nxt - 1) * M + 4 * lane);

            double delta = key2d(km);
            if (usedm & 1) { u[p0] += delta; v0 -= delta; } else m0 -= delta;
            if (usedm & 2) { u[p1] += delta; v1 -= delta; } else m1 -= delta;
            if (usedm & 4) { u[p2] += delta; v2 -= delta; } else m2 -= delta;
            if (usedm & 8) { u[p3] += delta; v3 -= delta; } else m3 -= delta;
            if (lane == 0) u[t] += delta;        // virtual column: p[0] = t

            if (pjn == 0) break;
            j0 = jn; u0 = u_next; r4 = r4n;
        }

        // augment: while j != 0: j1 = way[j]; p[j] = p[j1] (p[0] == t)
        int jj = jn;
        while (jj != 0) {
            int s = (jj - 1) & 3, o = (jj - 1) >> 2;
            int wv = sel4(w0, w1, w2, w3, s);
            int j1 = __shfl(wv, o, 64);
            int pn;
            if (j1 == 0) pn = t;
            else {
                int s1 = (j1 - 1) & 3, o1 = (j1 - 1) >> 2;
                int pv = sel4(p0, p1, p2, p3, s1);
                pn = __shfl(pv, o1, 64);
            }
            if (o == lane) {
                if (s == 0) p0 = pn;
                else if (s == 1) p1 = pn;
                else if (s == 2) p2 = pn;
                else p3 = pn;
            }
            jj = j1;
        }
    }

    // matched sums over real pairs: pred-col j (owned) matched to target p[j]
    double sm = 0.0, ss = 0.0, sb = 0.0;
#pragma unroll
    for (int s = 0; s < 4; ++s) {
        int pt = sel4(p0, p1, p2, p3, s);
        if (pt != 0) {
            int r = j_base + s - 1;   // pred index
            int c = pt - 1;           // target index
            sm += (double)C[(size_t)c * M + r];
            sb += (double)boxc[((size_t)b * M + r) * N + c];
            ss += (double)fmaxf(0.0f, t_score[b * N + c] - p_score[b * M + r]);
        }
    }
#pragma unroll
    for (int off = 1; off < 64; off <<= 1) {
        sm += __shfl_xor(sm, off, 64);
        ss += __shfl_xor(ss, off, 64);
        sb += __shfl_xor(sb, off, 64);
    }
    if (lane == 0) {
        out[0 * B + b] = (float)(sm / N);
        out[1 * B + b] = (float)(ss / N);
        out[2 * B + b] = (float)(sb / N);
    }
}

extern "C" void kernel_launch(void* const* d_in, const int* in_sizes, int n_in,
                              void* d_out, int out_size, void* d_ws, size_t ws_size,
                              hipStream_t stream) {
    int B = out_size / 3;                 // out is [3, B]
    int M = in_sizes[1] / B;              // pred_score [B, M]
    int N = in_sizes[3] / B;              // target_score [B, N]

    const float* p_box   = (const float*)d_in[0];
    const float* p_score = (const float*)d_in[1];
    const float* t_box   = (const float*)d_in[2];
    const float* t_score = (const float*)d_in[3];
    float* out = (float*)d_out;

    float* Ct   = (float*)d_ws;                       // [B, N, M]
    float* boxc = Ct + (size_t)B * N * M;             // [B, M, N]

    int total = B * M * N;
    cost_kernel<<<(total + 255) / 256, 256, 0, stream>>>(
        p_box, p_score, t_box, t_score, Ct, boxc, B, M, N);
    hungarian_rect<<<B, 64, 0, stream>>>(
        Ct, boxc, p_score, t_score, out, B, M, N);
}

// Round 4
// 986.751 us; speedup vs baseline: 21.3610x; 1.2778x over previous
//
#include <hip/hip_runtime.h>
#include <cmath>

#define MAXV 8

// ---------------------------------------------------------------------------
// Kernel 1: cost matrices for the RECTANGULAR problem (no padding).
// One thread per (b, n, m), m fastest. Writes:
//   Ct[b][n][m]  = score_cost + giou_cost   (transposed cost, coalesced rows)
//   boxc[b][m][n] = giou_cost
// Math mirrors the reference f32 op order exactly.
// ---------------------------------------------------------------------------
__global__ __launch_bounds__(256) void cost_kernel(
    const float* __restrict__ p_box, const float* __restrict__ p_score,
    const float* __restrict__ t_box, const float* __restrict__ t_score,
    float* __restrict__ Ct, float* __restrict__ boxc,
    int B, int M, int N)
{
    int g = blockIdx.x * 256 + threadIdx.x;
    int total = B * M * N;
    if (g >= total) return;
    int b = g / (M * N);
    int rem = g - b * M * N;
    int n = rem / M;
    int m = rem - n * M;

    const float* bp = p_box + ((size_t)b * M + m) * 5;
    const float* bt = t_box + ((size_t)b * N + n) * 5;
    float pcx = bp[0], pcy = bp[1], pw = bp[2], ph = bp[3], pth = bp[4];
    float tcx = bt[0], tcy = bt[1], tw = bt[2], th = bt[3], tth = bt[4];

    float pc = cosf(pth), ps = sinf(pth);
    float tc = cosf(tth), ts = sinf(tth);

    const float DX[4] = {-0.5f, 0.5f, 0.5f, -0.5f};
    const float DY[4] = {-0.5f, -0.5f, 0.5f, 0.5f};
    float cpx[4], cpy[4], ctx[4], cty[4];
#pragma unroll
    for (int k = 0; k < 4; k++) {
        float dx = DX[k] * pw, dy = DY[k] * ph;
        cpx[k] = pcx + dx * pc - dy * ps;
        cpy[k] = pcy + dx * ps + dy * pc;
        float dx2 = DX[k] * tw, dy2 = DY[k] * th;
        ctx[k] = tcx + dx2 * tc - dy2 * ts;
        cty[k] = tcy + dx2 * ts + dy2 * tc;
    }

    float px[MAXV], py[MAXV];
#pragma unroll
    for (int k = 0; k < MAXV; k++) {
        px[k] = (k < 4) ? cpx[k] : 0.0f;
        py[k] = (k < 4) ? cpy[k] : 0.0f;
    }
    int cnt = 4;

#pragma unroll
    for (int e = 0; e < 4; e++) {
        float ax = ctx[e], ay = cty[e];
        float bx2 = ctx[(e + 1) & 3], by2 = cty[(e + 1) & 3];
        float dx = bx2 - ax, dy = by2 - ay;
        float qx[MAXV], qy[MAXV];
#pragma unroll
        for (int k = 0; k < MAXV; k++) { qx[k] = 0.0f; qy[k] = 0.0f; }
        int nc = 0;
#pragma unroll
        for (int i = 0; i < MAXV; i++) {
            if (i < cnt) {
                bool wrap = !(i + 1 < cnt);
                float nx = wrap ? px[0] : px[(i + 1) & 7];
                float ny = wrap ? py[0] : py[(i + 1) & 7];
                float sc = dx * (py[i] - ay) - dy * (px[i] - ax);
                float sn = dx * (ny - ay) - dy * (nx - ax);
                bool inc = (sc >= 0.0f), inn = (sn >= 0.0f);
                float den = sc - sn;
                if (!(fabsf(den) > 1e-9f)) den = 1e-9f;
                float t = sc / den;
                float ix = px[i] + t * (nx - px[i]);
                float iy = py[i] + t * (ny - py[i]);
                if (inc) {
                    if (nc < MAXV) { qx[nc] = px[i]; qy[nc] = py[i]; }
                    nc++;
                }
                if (inc != inn) {
                    if (nc < MAXV) { qx[nc] = ix; qy[nc] = iy; }
                    nc++;
                }
            }
        }
        cnt = (nc > MAXV) ? MAXV : nc;
#pragma unroll
        for (int k = 0; k < MAXV; k++) {
            px[k] = (k < cnt) ? qx[k] : 0.0f;
            py[k] = (k < cnt) ? qy[k] : 0.0f;
        }
    }

    float a2 = 0.0f;
#pragma unroll
    for (int i = 0; i < MAXV; i++) {
        if (i < cnt) {
            bool wrap = !(i + 1 < cnt);
            float nx = wrap ? px[0] : px[(i + 1) & 7];
            float ny = wrap ? py[0] : py[(i + 1) & 7];
            a2 += px[i] * ny - nx * py[i];
        }
    }
    float inter = 0.5f * fabsf(a2);

    float uni = tw * th + pw * ph - inter;

    float xmin = ctx[0], xmax = ctx[0], ymin = cty[0], ymax = cty[0];
#pragma unroll
    for (int k = 1; k < 4; k++) {
        xmin = fminf(xmin, ctx[k]); xmax = fmaxf(xmax, ctx[k]);
        ymin = fminf(ymin, cty[k]); ymax = fmaxf(ymax, cty[k]);
    }
#pragma unroll
    for (int k = 0; k < 4; k++) {
        xmin = fminf(xmin, cpx[k]); xmax = fmaxf(xmax, cpx[k]);
        ymin = fminf(ymin, cpy[k]); ymax = fmaxf(ymax, cpy[k]);
    }
    float enc = (xmax - xmin) * (ymax - ymin);

    float giou = inter / uni - (enc - uni) / enc;
    float bc = 1.0f - giou;
    float scst = fmaxf(0.0f, t_score[b * N + n] - p_score[b * M + m]);

    Ct[((size_t)b * N + n) * M + m] = scst + bc;
    boxc[((size_t)b * M + m) * N + n] = bc;
}

// ---------------------------------------------------------------------------
// Kernel 1.5: per-target-row (min, first argmin) over the M pred columns.
// One 64-thread block per (b, t) row. Feeds JV column-reduction init.
// ---------------------------------------------------------------------------
__global__ __launch_bounds__(64) void rowmin_kernel(
    const float* __restrict__ Ct, float* __restrict__ rmv,
    int* __restrict__ rmj, int M)
{
    int bt = blockIdx.x;
    int lane = threadIdx.x;
    const float* row = Ct + (size_t)bt * M;

    float bv = 1e30f; int bj = 0;
    for (int c = 4 * lane; c < M; c += 256) {
        float4 v = *reinterpret_cast<const float4*>(row + c);
        if (v.x < bv) { bv = v.x; bj = c; }
        if (v.y < bv) { bv = v.y; bj = c + 1; }
        if (v.z < bv) { bv = v.z; bj = c + 2; }
        if (v.w < bv) { bv = v.w; bj = c + 3; }
    }
#pragma unroll
    for (int off = 1; off < 64; off <<= 1) {
        float ov = __shfl_xor(bv, off, 64);
        int oj = __shfl_xor(bj, off, 64);
        if (ov < bv || (ov == bv && oj < bj)) { bv = ov; bj = oj; }
    }
    if (lane == 0) { rmv[bt] = bv; rmj[bt] = bj; }
}

// ---------------------------------------------------------------------------
// Kernel 2: rectangular JV Hungarian with column-reduction init.
// Single wave per batch, barrier-free hot loop. Lane l owns pred-columns
// 4l+1..4l+4 (1-based). u[targets] in LDS; v/minv/way/p in registers.
// Init: u[t] = rowmin (dual-feasible, rc >= 0 with exact 0 at argmin since
// f32->f64 is exact); greedy-match t -> argmin col if free. Dijkstra phases
// run only for the leftover unmatched targets. Final matching is the exact
// optimum (unique w.p. 1 for continuous data), so outputs == reference.
// ---------------------------------------------------------------------------
__device__ __forceinline__ int sel4(int a0, int a1, int a2, int a3, int s) {
    return s == 0 ? a0 : (s == 1 ? a1 : (s == 2 ? a2 : a3));
}

__global__ __launch_bounds__(64) void hungarian_rect(
    const float* __restrict__ Ct, const float* __restrict__ boxc,
    const float* __restrict__ p_score, const float* __restrict__ t_score,
    const float* __restrict__ rmv, const int* __restrict__ rmj,
    float* __restrict__ out, int B, int M, int N)
{
    const double DINF = 1e30;
    int b = blockIdx.x;
    int lane = threadIdx.x;
    const float* C = Ct + (size_t)b * N * M;   // [N][M] rows contiguous

    __shared__ double u[257];                  // indexed by target 1..N
    __shared__ int ulist[257];                 // targets needing Dijkstra

    // u[t] = row min (column-reduction duals)
    for (int k = lane; k < N; k += 64) u[k + 1] = (double)rmv[b * N + k];
    __syncthreads();

    const int j_base = 4 * lane + 1;           // first owned pred-col (1-based)
    double v0 = 0.0, v1 = 0.0, v2 = 0.0, v3 = 0.0;
    double m0, m1, m2, m3;
    int p0 = 0, p1 = 0, p2 = 0, p3 = 0;        // pred-col -> matched target
    int w0 = 0, w1 = 0, w2 = 0, w3 = 0;

    // preload row-argmins into registers (slot q holds target q*64+lane)
    int rj0 = 0, rj1 = 0, rj2 = 0, rj3 = 0;
    {
        int base = b * N;
        if (lane < N)        rj0 = rmj[base + lane];
        if (64 + lane < N)   rj1 = rmj[base + 64 + lane];
        if (128 + lane < N)  rj2 = rmj[base + 128 + lane];
        if (192 + lane < N)  rj3 = rmj[base + 192 + lane];
    }

    // greedy pass: match t to its argmin column if that column is free
    int ucnt = 0;
    for (int t = 1; t <= N; ++t) {
        int q = (t - 1) >> 6, ln = (t - 1) & 63;
        int jm = __shfl(sel4(rj0, rj1, rj2, rj3, q), ln, 64);  // 0-based col
        int o = jm >> 2, s = jm & 3;
        int pv = __shfl(sel4(p0, p1, p2, p3, s), o, 64);
        if (pv == 0) {
            if (lane == o) {
                if (s == 0) p0 = t;
                else if (s == 1) p1 = t;
                else if (s == 2) p2 = t;
                else p3 = t;
            }
        } else {
            if (lane == 0) ulist[ucnt] = t;
            ucnt++;
        }
    }
    __syncthreads();

    // Dijkstra phases for unmatched targets
    for (int uk = 0; uk < ucnt; ++uk) {
        int t = ulist[uk];
        m0 = DINF; m1 = DINF; m2 = DINF; m3 = DINF;
        int usedm = 0;
        int j0 = 0;                 // current pred-col (0 = virtual)
        double u0 = u[t];
        float4 r4 = *reinterpret_cast<const float4*>(
            C + (size_t)(t - 1) * M + 4 * lane);
        int jn;

        while (true) {
            if (j0 != 0 && ((j0 - 1) >> 2) == lane) usedm |= 1 << ((j0 - 1) & 3);

            // cur = (c - u) - v ; strict < update (free cols only)
            double a0 = DINF, a1 = DINF, a2d = DINF, a3 = DINF;
            if (!(usedm & 1)) {
                double cur = ((double)r4.x - u0) - v0;
                if (cur < m0) { m0 = cur; w0 = j0; }
                a0 = m0;
            }
            if (!(usedm & 2)) {
                double cur = ((double)r4.y - u0) - v1;
                if (cur < m1) { m1 = cur; w1 = j0; }
                a1 = m1;
            }
            if (!(usedm & 4)) {
                double cur = ((double)r4.z - u0) - v2;
                if (cur < m2) { m2 = cur; w2 = j0; }
                a2d = m2;
            }
            if (!(usedm & 8)) {
                double cur = ((double)r4.w - u0) - v3;
                if (cur < m3) { m3 = cur; w3 = j0; }
                a3 = m3;
            }

            // lane-local (min, smallest slot)
            double av = a0; int sa = 0;
            if (a1 < av)  { av = a1;  sa = 1; }
            if (a2d < av) { av = a2d; sa = 2; }
            if (a3 < av)  { av = a3;  sa = 3; }

            // wave min via fmin butterfly (all values >= 0, no NaN;
            // min is order-invariant -> identical result on all lanes)
            double wm = av;
#pragma unroll
            for (int off = 1; off < 64; off <<= 1)
                wm = fmin(wm, __shfl_xor(wm, off, 64));

            unsigned long long ball = __ballot(av == wm);
            int owner = __builtin_ctzll(ball);   // lowest lane = smallest j
            int pk = (j_base + sa) | (sel4(p0, p1, p2, p3, sa) << 9);
            pk = __shfl(pk, owner, 64);
            int jn_ = pk & 511, pjn = pk >> 9;

            // early reads for next iteration (addresses provably untouched
            // by this iteration's u writes)
            int nxt = (pjn > 0) ? pjn : t;
            double u_next = u[nxt];
            float4 r4n = *reinterpret_cast<const float4*>(
                C + (size_t)(nxt - 1) * M + 4 * lane);

            double delta = wm;
            if (usedm & 1) { u[p0] += delta; v0 -= delta; } else m0 -= delta;
            if (usedm & 2) { u[p1] += delta; v1 -= delta; } else m1 -= delta;
            if (usedm & 4) { u[p2] += delta; v2 -= delta; } else m2 -= delta;
            if (usedm & 8) { u[p3] += delta; v3 -= delta; } else m3 -= delta;
            if (lane == 0) u[t] += delta;        // virtual column: p[0] = t

            jn = jn_;
            if (pjn == 0) break;
            j0 = jn_; u0 = u_next; r4 = r4n;
        }

        // augment: while j != 0: j1 = way[j]; p[j] = p[j1] (p[0] == t)
        int jj = jn;
        while (jj != 0) {
            int s = (jj - 1) & 3, o = (jj - 1) >> 2;
            int wv = sel4(w0, w1, w2, w3, s);
            int j1 = __shfl(wv, o, 64);
            int pn;
            if (j1 == 0) pn = t;
            else {
                int s1 = (j1 - 1) & 3, o1 = (j1 - 1) >> 2;
                int pv = sel4(p0, p1, p2, p3, s1);
                pn = __shfl(pv, o1, 64);
            }
            if (o == lane) {
                if (s == 0) p0 = pn;
                else if (s == 1) p1 = pn;
                else if (s == 2) p2 = pn;
                else p3 = pn;
            }
            jj = j1;
        }
    }

    // matched sums over real pairs: pred-col j (owned) matched to target p[j]
    double sm = 0.0, ss = 0.0, sb = 0.0;
#pragma unroll
    for (int s = 0; s < 4; ++s) {
        int pt = sel4(p0, p1, p2, p3, s);
        if (pt != 0) {
            int r = j_base + s - 1;   // pred index
            int c = pt - 1;           // target index
            sm += (double)C[(size_t)c * M + r];
            sb += (double)boxc[((size_t)b * M + r) * N + c];
            ss += (double)fmaxf(0.0f, t_score[b * N + c] - p_score[b * M + r]);
        }
    }
#pragma unroll
    for (int off = 1; off < 64; off <<= 1) {
        sm += __shfl_xor(sm, off, 64);
        ss += __shfl_xor(ss, off, 64);
        sb += __shfl_xor(sb, off, 64);
    }
    if (lane == 0) {
        out[0 * B + b] = (float)(sm / N);
        out[1 * B + b] = (float)(ss / N);
        out[2 * B + b] = (float)(sb / N);
    }
}

extern "C" void kernel_launch(void* const* d_in, const int* in_sizes, int n_in,
                              void* d_out, int out_size, void* d_ws, size_t ws_size,
                              hipStream_t stream) {
    int B = out_size / 3;                 // out is [3, B]
    int M = in_sizes[1] / B;              // pred_score [B, M]
    int N = in_sizes[3] / B;              // target_score [B, N]

    const float* p_box   = (const float*)d_in[0];
    const float* p_score = (const float*)d_in[1];
    const float* t_box   = (const float*)d_in[2];
    const float* t_score = (const float*)d_in[3];
    float* out = (float*)d_out;

    float* Ct   = (float*)d_ws;                       // [B, N, M]
    float* boxc = Ct + (size_t)B * N * M;             // [B, M, N]
    float* rmv  = boxc + (size_t)B * M * N;           // [B, N]
    int*   rmj  = (int*)(rmv + (size_t)B * N);        // [B, N]

    int total = B * M * N;
    cost_kernel<<<(total + 255) / 256, 256, 0, stream>>>(
        p_box, p_score, t_box, t_score, Ct, boxc, B, M, N);
    rowmin_kernel<<<B * N, 64, 0, stream>>>(Ct, rmv, rmj, M);
    hungarian_rect<<<B, 64, 0, stream>>>(
        Ct, boxc, p_score, t_score, rmv, rmj, out, B, M, N);
}

// Round 5
// 819.947 us; speedup vs baseline: 25.7065x; 1.2034x over previous
//
#include <hip/hip_runtime.h>
#include <cmath>

#define MAXV 8

// ---------------------------------------------------------------------------
// Kernel 1: cost matrices for the RECTANGULAR problem (no padding).
// One thread per (b, n, m), m fastest. Writes:
//   Ct[b][n][m]  = score_cost + giou_cost   (transposed cost, coalesced rows)
//   boxc[b][m][n] = giou_cost
// Math mirrors the reference f32 op order exactly.
// ---------------------------------------------------------------------------
__global__ __launch_bounds__(256) void cost_kernel(
    const float* __restrict__ p_box, const float* __restrict__ p_score,
    const float* __restrict__ t_box, const float* __restrict__ t_score,
    float* __restrict__ Ct, float* __restrict__ boxc,
    int B, int M, int N)
{
    int g = blockIdx.x * 256 + threadIdx.x;
    int total = B * M * N;
    if (g >= total) return;
    int b = g / (M * N);
    int rem = g - b * M * N;
    int n = rem / M;
    int m = rem - n * M;

    const float* bp = p_box + ((size_t)b * M + m) * 5;
    const float* bt = t_box + ((size_t)b * N + n) * 5;
    float pcx = bp[0], pcy = bp[1], pw = bp[2], ph = bp[3], pth = bp[4];
    float tcx = bt[0], tcy = bt[1], tw = bt[2], th = bt[3], tth = bt[4];

    float pc = cosf(pth), ps = sinf(pth);
    float tc = cosf(tth), ts = sinf(tth);

    const float DX[4] = {-0.5f, 0.5f, 0.5f, -0.5f};
    const float DY[4] = {-0.5f, -0.5f, 0.5f, 0.5f};
    float cpx[4], cpy[4], ctx[4], cty[4];
#pragma unroll
    for (int k = 0; k < 4; k++) {
        float dx = DX[k] * pw, dy = DY[k] * ph;
        cpx[k] = pcx + dx * pc - dy * ps;
        cpy[k] = pcy + dx * ps + dy * pc;
        float dx2 = DX[k] * tw, dy2 = DY[k] * th;
        ctx[k] = tcx + dx2 * tc - dy2 * ts;
        cty[k] = tcy + dx2 * ts + dy2 * tc;
    }

    float px[MAXV], py[MAXV];
#pragma unroll
    for (int k = 0; k < MAXV; k++) {
        px[k] = (k < 4) ? cpx[k] : 0.0f;
        py[k] = (k < 4) ? cpy[k] : 0.0f;
    }
    int cnt = 4;

#pragma unroll
    for (int e = 0; e < 4; e++) {
        float ax = ctx[e], ay = cty[e];
        float bx2 = ctx[(e + 1) & 3], by2 = cty[(e + 1) & 3];
        float dx = bx2 - ax, dy = by2 - ay;
        float qx[MAXV], qy[MAXV];
#pragma unroll
        for (int k = 0; k < MAXV; k++) { qx[k] = 0.0f; qy[k] = 0.0f; }
        int nc = 0;
#pragma unroll
        for (int i = 0; i < MAXV; i++) {
            if (i < cnt) {
                bool wrap = !(i + 1 < cnt);
                float nx = wrap ? px[0] : px[(i + 1) & 7];
                float ny = wrap ? py[0] : py[(i + 1) & 7];
                float sc = dx * (py[i] - ay) - dy * (px[i] - ax);
                float sn = dx * (ny - ay) - dy * (nx - ax);
                bool inc = (sc >= 0.0f), inn = (sn >= 0.0f);
                float den = sc - sn;
                if (!(fabsf(den) > 1e-9f)) den = 1e-9f;
                float t = sc / den;
                float ix = px[i] + t * (nx - px[i]);
                float iy = py[i] + t * (ny - py[i]);
                if (inc) {
                    if (nc < MAXV) { qx[nc] = px[i]; qy[nc] = py[i]; }
                    nc++;
                }
                if (inc != inn) {
                    if (nc < MAXV) { qx[nc] = ix; qy[nc] = iy; }
                    nc++;
                }
            }
        }
        cnt = (nc > MAXV) ? MAXV : nc;
#pragma unroll
        for (int k = 0; k < MAXV; k++) {
            px[k] = (k < cnt) ? qx[k] : 0.0f;
            py[k] = (k < cnt) ? qy[k] : 0.0f;
        }
    }

    float a2 = 0.0f;
#pragma unroll
    for (int i = 0; i < MAXV; i++) {
        if (i < cnt) {
            bool wrap = !(i + 1 < cnt);
            float nx = wrap ? px[0] : px[(i + 1) & 7];
            float ny = wrap ? py[0] : py[(i + 1) & 7];
            a2 += px[i] * ny - nx * py[i];
        }
    }
    float inter = 0.5f * fabsf(a2);

    float uni = tw * th + pw * ph - inter;

    float xmin = ctx[0], xmax = ctx[0], ymin = cty[0], ymax = cty[0];
#pragma unroll
    for (int k = 1; k < 4; k++) {
        xmin = fminf(xmin, ctx[k]); xmax = fmaxf(xmax, ctx[k]);
        ymin = fminf(ymin, cty[k]); ymax = fmaxf(ymax, cty[k]);
    }
#pragma unroll
    for (int k = 0; k < 4; k++) {
        xmin = fminf(xmin, cpx[k]); xmax = fmaxf(xmax, cpx[k]);
        ymin = fminf(ymin, cpy[k]); ymax = fmaxf(ymax, cpy[k]);
    }
    float enc = (xmax - xmin) * (ymax - ymin);

    float giou = inter / uni - (enc - uni) / enc;
    float bc = 1.0f - giou;
    float scst = fmaxf(0.0f, t_score[b * N + n] - p_score[b * M + m]);

    Ct[((size_t)b * N + n) * M + m] = scst + bc;
    boxc[((size_t)b * M + m) * N + n] = bc;
}

// ---------------------------------------------------------------------------
// Kernel 1.5: per-target-row (min, first argmin) over the M pred columns.
// ---------------------------------------------------------------------------
__global__ __launch_bounds__(64) void rowmin_kernel(
    const float* __restrict__ Ct, float* __restrict__ rmv,
    int* __restrict__ rmj, int M)
{
    int bt = blockIdx.x;
    int lane = threadIdx.x;
    const float* row = Ct + (size_t)bt * M;

    float bv = 1e30f; int bj = 0;
    for (int c = 4 * lane; c < M; c += 256) {
        float4 v = *reinterpret_cast<const float4*>(row + c);
        if (v.x < bv) { bv = v.x; bj = c; }
        if (v.y < bv) { bv = v.y; bj = c + 1; }
        if (v.z < bv) { bv = v.z; bj = c + 2; }
        if (v.w < bv) { bv = v.w; bj = c + 3; }
    }
#pragma unroll
    for (int off = 1; off < 64; off <<= 1) {
        float ov = __shfl_xor(bv, off, 64);
        int oj = __shfl_xor(bj, off, 64);
        if (ov < bv || (ov == bv && oj < bj)) { bv = ov; bj = oj; }
    }
    if (lane == 0) { rmv[bt] = bv; rmj[bt] = bj; }
}

// ---------------------------------------------------------------------------
// Kernel 2: rectangular JV Hungarian, column-reduction init, single wave per
// batch. All reduced costs are >= 0 in exact f64 (u[t]=rowmin exact at f32
// granularity, v<=0), so positive-double bit patterns order as u64 and the
// wave min runs on a DPP ladder (row_shr 1/2/4/8 + row_bcast 15/31) at VALU
// latency instead of a ds_bpermute butterfly. All uniform-lane cross-lane
// reads use v_readlane. Matching identical to numpy's (unique optimum).
// ---------------------------------------------------------------------------
__device__ __forceinline__ int sel4(int a0, int a1, int a2, int a3, int s) {
    return s == 0 ? a0 : (s == 1 ? a1 : (s == 2 ? a2 : a3));
}

// min into kv from the DPP-shifted neighbor; invalid lanes read +inf (old).
#define DPP_MIN_STAGE(kv, CTRL) do {                                          \
    int _lo = __builtin_amdgcn_update_dpp(0, (int)(kv), CTRL, 0xf, 0xf, false);\
    int _hi = __builtin_amdgcn_update_dpp(0x7FF00000, (int)((kv) >> 32),       \
                                          CTRL, 0xf, 0xf, false);              \
    unsigned long long _o =                                                    \
        ((unsigned long long)(unsigned)_hi << 32) | (unsigned)_lo;             \
    if (_o < (kv)) (kv) = _o;                                                  \
} while (0)

__global__ __launch_bounds__(64) void hungarian_rect(
    const float* __restrict__ Ct, const float* __restrict__ boxc,
    const float* __restrict__ p_score, const float* __restrict__ t_score,
    const float* __restrict__ rmv, const int* __restrict__ rmj,
    float* __restrict__ out, int B, int M, int N)
{
    const double DINF = 1e30;
    int b = blockIdx.x;
    int lane = threadIdx.x;
    const float* C = Ct + (size_t)b * N * M;   // [N][M] rows contiguous

    __shared__ double u[257];                  // indexed by target 1..N
    __shared__ int ulist[257];                 // targets needing Dijkstra

    for (int k = lane; k < N; k += 64) u[k + 1] = (double)rmv[b * N + k];
    __syncthreads();

    const int j_base = 4 * lane + 1;           // first owned pred-col (1-based)
    double v0 = 0.0, v1 = 0.0, v2 = 0.0, v3 = 0.0;
    double m0, m1, m2, m3;
    int p0 = 0, p1 = 0, p2 = 0, p3 = 0;        // pred-col -> matched target
    int w0 = 0, w1 = 0, w2 = 0, w3 = 0;

    // preload row-argmins (slot q holds target q*64+lane)
    int rj0 = 0, rj1 = 0, rj2 = 0, rj3 = 0;
    {
        int base = b * N;
        if (lane < N)        rj0 = rmj[base + lane];
        if (64 + lane < N)   rj1 = rmj[base + 64 + lane];
        if (128 + lane < N)  rj2 = rmj[base + 128 + lane];
        if (192 + lane < N)  rj3 = rmj[base + 192 + lane];
    }

    // greedy pass: match t to its argmin column if that column is free
    int ucnt = 0;
    for (int t = 1; t <= N; ++t) {
        int q = (t - 1) >> 6, ln = (t - 1) & 63;
        int jm = __builtin_amdgcn_readlane(sel4(rj0, rj1, rj2, rj3, q), ln);
        int o = jm >> 2, s = jm & 3;
        int pv = __builtin_amdgcn_readlane(sel4(p0, p1, p2, p3, s), o);
        if (pv == 0) {
            if (lane == o) {
                if (s == 0) p0 = t;
                else if (s == 1) p1 = t;
                else if (s == 2) p2 = t;
                else p3 = t;
            }
        } else {
            if (lane == 0) ulist[ucnt] = t;
            ucnt++;
        }
    }
    __syncthreads();

    // Dijkstra phases for unmatched targets
    for (int uk = 0; uk < ucnt; ++uk) {
        int t = ulist[uk];
        m0 = DINF; m1 = DINF; m2 = DINF; m3 = DINF;
        int usedm = 0;
        int j0 = 0;                 // current pred-col (0 = virtual)
        double u0 = u[t];
        float4 r4 = *reinterpret_cast<const float4*>(
            C + (size_t)(t - 1) * M + 4 * lane);
        int jn;

        while (true) {
            if (j0 != 0 && ((j0 - 1) >> 2) == lane) usedm |= 1 << ((j0 - 1) & 3);

            // cur = (c - u) - v ; strict < update (free cols only)
            double a0 = DINF, a1 = DINF, a2d = DINF, a3 = DINF;
            if (!(usedm & 1)) {
                double cur = ((double)r4.x - u0) - v0;
                if (cur < m0) { m0 = cur; w0 = j0; }
                a0 = m0;
            }
            if (!(usedm & 2)) {
                double cur = ((double)r4.y - u0) - v1;
                if (cur < m1) { m1 = cur; w1 = j0; }
                a1 = m1;
            }
            if (!(usedm & 4)) {
                double cur = ((double)r4.z - u0) - v2;
                if (cur < m2) { m2 = cur; w2 = j0; }
                a2d = m2;
            }
            if (!(usedm & 8)) {
                double cur = ((double)r4.w - u0) - v3;
                if (cur < m3) { m3 = cur; w3 = j0; }
                a3 = m3;
            }

            // lane-local (min, smallest slot)
            double av = a0; int sa = 0;
            if (a1 < av)  { av = a1;  sa = 1; }
            if (a2d < av) { av = a2d; sa = 2; }
            if (a3 < av)  { av = a3;  sa = 3; }

            // wave min on u64 bits (all values >= 0 finite) via DPP ladder;
            // lane 63 ends with the full-wave min.
            unsigned long long akey =
                (unsigned long long)__double_as_longlong(av);
            unsigned long long kv = akey;
            DPP_MIN_STAGE(kv, 0x111);   // row_shr:1
            DPP_MIN_STAGE(kv, 0x112);   // row_shr:2
            DPP_MIN_STAGE(kv, 0x114);   // row_shr:4
            DPP_MIN_STAGE(kv, 0x118);   // row_shr:8
            DPP_MIN_STAGE(kv, 0x142);   // row_bcast:15
            DPP_MIN_STAGE(kv, 0x143);   // row_bcast:31
            int wlo = __builtin_amdgcn_readlane((int)kv, 63);
            int whi = __builtin_amdgcn_readlane((int)(kv >> 32), 63);
            unsigned long long wmb =
                ((unsigned long long)(unsigned)whi << 32) | (unsigned)wlo;

            unsigned long long ball = __ballot(akey == wmb);
            int owner = __builtin_ctzll(ball);   // lowest lane = smallest col
            int pk = (j_base + sa) | (sel4(p0, p1, p2, p3, sa) << 9);
            pk = __builtin_amdgcn_readlane(pk, owner);
            int jn_ = pk & 511, pjn = pk >> 9;

            // early reads for next iteration (addresses provably untouched
            // by this iteration's u writes)
            int nxt = (pjn > 0) ? pjn : t;
            double u_next = u[nxt];
            float4 r4n = *reinterpret_cast<const float4*>(
                C + (size_t)(nxt - 1) * M + 4 * lane);

            double delta = __longlong_as_double((long long)wmb);
            if (usedm & 1) { u[p0] += delta; v0 -= delta; } else m0 -= delta;
            if (usedm & 2) { u[p1] += delta; v1 -= delta; } else m1 -= delta;
            if (usedm & 4) { u[p2] += delta; v2 -= delta; } else m2 -= delta;
            if (usedm & 8) { u[p3] += delta; v3 -= delta; } else m3 -= delta;
            if (lane == 0) u[t] += delta;        // virtual column: p[0] = t

            jn = jn_;
            if (pjn == 0) break;
            j0 = jn_; u0 = u_next; r4 = r4n;
        }

        // augment: stream p[j_k] = p_old[j_{k+1}] one step behind the
        // traversal; one readlane per step (packed way|p).
        int jj = jn, prev = 0;
        while (true) {
            int idx = jj - 1;
            int o = idx >> 2, s = idx & 3;
            int packv = sel4(w0, w1, w2, w3, s) |
                        (sel4(p0, p1, p2, p3, s) << 9);
            packv = __builtin_amdgcn_readlane(packv, o);
            int wv = packv & 511, pold = packv >> 9;
            if (prev != 0) {
                int pi = prev - 1;
                if (lane == (pi >> 2)) {
                    int sp = pi & 3;
                    if (sp == 0) p0 = pold;
                    else if (sp == 1) p1 = pold;
                    else if (sp == 2) p2 = pold;
                    else p3 = pold;
                }
            }
            if (wv == 0) {
                if (lane == o) {
                    if (s == 0) p0 = t;
                    else if (s == 1) p1 = t;
                    else if (s == 2) p2 = t;
                    else p3 = t;
                }
                break;
            }
            prev = jj; jj = wv;
        }
    }

    // matched sums over real pairs: pred-col j (owned) matched to target p[j]
    double sm = 0.0, ss = 0.0, sb = 0.0;
#pragma unroll
    for (int s = 0; s < 4; ++s) {
        int pt = sel4(p0, p1, p2, p3, s);
        if (pt != 0) {
            int r = j_base + s - 1;   // pred index
            int c = pt - 1;           // target index
            sm += (double)C[(size_t)c * M + r];
            sb += (double)boxc[((size_t)b * M + r) * N + c];
            ss += (double)fmaxf(0.0f, t_score[b * N + c] - p_score[b * M + r]);
        }
    }
#pragma unroll
    for (int off = 1; off < 64; off <<= 1) {
        sm += __shfl_xor(sm, off, 64);
        ss += __shfl_xor(ss, off, 64);
        sb += __shfl_xor(sb, off, 64);
    }
    if (lane == 0) {
        out[0 * B + b] = (float)(sm / N);
        out[1 * B + b] = (float)(ss / N);
        out[2 * B + b] = (float)(sb / N);
    }
}

extern "C" void kernel_launch(void* const* d_in, const int* in_sizes, int n_in,
                              void* d_out, int out_size, void* d_ws, size_t ws_size,
                              hipStream_t stream) {
    int B = out_size / 3;                 // out is [3, B]
    int M = in_sizes[1] / B;              // pred_score [B, M]
    int N = in_sizes[3] / B;              // target_score [B, N]

    const float* p_box   = (const float*)d_in[0];
    const float* p_score = (const float*)d_in[1];
    const float* t_box   = (const float*)d_in[2];
    const float* t_score = (const float*)d_in[3];
    float* out = (float*)d_out;

    float* Ct   = (float*)d_ws;                       // [B, N, M]
    float* boxc = Ct + (size_t)B * N * M;             // [B, M, N]
    float* rmv  = boxc + (size_t)B * M * N;           // [B, N]
    int*   rmj  = (int*)(rmv + (size_t)B * N);        // [B, N]

    int total = B * M * N;
    cost_kernel<<<(total + 255) / 256, 256, 0, stream>>>(
        p_box, p_score, t_box, t_score, Ct, boxc, B, M, N);
    rowmin_kernel<<<B * N, 64, 0, stream>>>(Ct, rmv, rmj, M);
    hungarian_rect<<<B, 64, 0, stream>>>(
        Ct, boxc, p_score, t_score, rmv, rmj, out, B, M, N);
}

// Round 6
// 696.481 us; speedup vs baseline: 30.2635x; 1.1773x over previous
//
#include <hip/hip_runtime.h>
#include <cmath>

#define MAXV 8

// ---------------------------------------------------------------------------
// Kernel 1: cost matrices for the RECTANGULAR problem (no padding).
// One thread per (b, n, m), m fastest. Writes:
//   Ct[b][n][m]  = score_cost + giou_cost   (transposed cost, coalesced rows)
//   boxc[b][m][n] = giou_cost
// Math mirrors the reference f32 op order exactly.
// ---------------------------------------------------------------------------
__global__ __launch_bounds__(256) void cost_kernel(
    const float* __restrict__ p_box, const float* __restrict__ p_score,
    const float* __restrict__ t_box, const float* __restrict__ t_score,
    float* __restrict__ Ct, float* __restrict__ boxc,
    int B, int M, int N)
{
    int g = blockIdx.x * 256 + threadIdx.x;
    int total = B * M * N;
    if (g >= total) return;
    int b = g / (M * N);
    int rem = g - b * M * N;
    int n = rem / M;
    int m = rem - n * M;

    const float* bp = p_box + ((size_t)b * M + m) * 5;
    const float* bt = t_box + ((size_t)b * N + n) * 5;
    float pcx = bp[0], pcy = bp[1], pw = bp[2], ph = bp[3], pth = bp[4];
    float tcx = bt[0], tcy = bt[1], tw = bt[2], th = bt[3], tth = bt[4];

    float pc = cosf(pth), ps = sinf(pth);
    float tc = cosf(tth), ts = sinf(tth);

    const float DX[4] = {-0.5f, 0.5f, 0.5f, -0.5f};
    const float DY[4] = {-0.5f, -0.5f, 0.5f, 0.5f};
    float cpx[4], cpy[4], ctx[4], cty[4];
#pragma unroll
    for (int k = 0; k < 4; k++) {
        float dx = DX[k] * pw, dy = DY[k] * ph;
        cpx[k] = pcx + dx * pc - dy * ps;
        cpy[k] = pcy + dx * ps + dy * pc;
        float dx2 = DX[k] * tw, dy2 = DY[k] * th;
        ctx[k] = tcx + dx2 * tc - dy2 * ts;
        cty[k] = tcy + dx2 * ts + dy2 * tc;
    }

    float px[MAXV], py[MAXV];
#pragma unroll
    for (int k = 0; k < MAXV; k++) {
        px[k] = (k < 4) ? cpx[k] : 0.0f;
        py[k] = (k < 4) ? cpy[k] : 0.0f;
    }
    int cnt = 4;

#pragma unroll
    for (int e = 0; e < 4; e++) {
        float ax = ctx[e], ay = cty[e];
        float bx2 = ctx[(e + 1) & 3], by2 = cty[(e + 1) & 3];
        float dx = bx2 - ax, dy = by2 - ay;
        float qx[MAXV], qy[MAXV];
#pragma unroll
        for (int k = 0; k < MAXV; k++) { qx[k] = 0.0f; qy[k] = 0.0f; }
        int nc = 0;
#pragma unroll
        for (int i = 0; i < MAXV; i++) {
            if (i < cnt) {
                bool wrap = !(i + 1 < cnt);
                float nx = wrap ? px[0] : px[(i + 1) & 7];
                float ny = wrap ? py[0] : py[(i + 1) & 7];
                float sc = dx * (py[i] - ay) - dy * (px[i] - ax);
                float sn = dx * (ny - ay) - dy * (nx - ax);
                bool inc = (sc >= 0.0f), inn = (sn >= 0.0f);
                float den = sc - sn;
                if (!(fabsf(den) > 1e-9f)) den = 1e-9f;
                float t = sc / den;
                float ix = px[i] + t * (nx - px[i]);
                float iy = py[i] + t * (ny - py[i]);
                if (inc) {
                    if (nc < MAXV) { qx[nc] = px[i]; qy[nc] = py[i]; }
                    nc++;
                }
                if (inc != inn) {
                    if (nc < MAXV) { qx[nc] = ix; qy[nc] = iy; }
                    nc++;
                }
            }
        }
        cnt = (nc > MAXV) ? MAXV : nc;
#pragma unroll
        for (int k = 0; k < MAXV; k++) {
            px[k] = (k < cnt) ? qx[k] : 0.0f;
            py[k] = (k < cnt) ? qy[k] : 0.0f;
        }
    }

    float a2 = 0.0f;
#pragma unroll
    for (int i = 0; i < MAXV; i++) {
        if (i < cnt) {
            bool wrap = !(i + 1 < cnt);
            float nx = wrap ? px[0] : px[(i + 1) & 7];
            float ny = wrap ? py[0] : py[(i + 1) & 7];
            a2 += px[i] * ny - nx * py[i];
        }
    }
    float inter = 0.5f * fabsf(a2);

    float uni = tw * th + pw * ph - inter;

    float xmin = ctx[0], xmax = ctx[0], ymin = cty[0], ymax = cty[0];
#pragma unroll
    for (int k = 1; k < 4; k++) {
        xmin = fminf(xmin, ctx[k]); xmax = fmaxf(xmax, ctx[k]);
        ymin = fminf(ymin, cty[k]); ymax = fmaxf(ymax, cty[k]);
    }
#pragma unroll
    for (int k = 0; k < 4; k++) {
        xmin = fminf(xmin, cpx[k]); xmax = fmaxf(xmax, cpx[k]);
        ymin = fminf(ymin, cpy[k]); ymax = fmaxf(ymax, cpy[k]);
    }
    float enc = (xmax - xmin) * (ymax - ymin);

    float giou = inter / uni - (enc - uni) / enc;
    float bc = 1.0f - giou;
    float scst = fmaxf(0.0f, t_score[b * N + n] - p_score[b * M + m]);

    Ct[((size_t)b * N + n) * M + m] = scst + bc;
    boxc[((size_t)b * M + m) * N + n] = bc;
}

// ---------------------------------------------------------------------------
// Kernel 1.5: per-target-row (min, first argmin) over the M pred columns.
// ---------------------------------------------------------------------------
__global__ __launch_bounds__(64) void rowmin_kernel(
    const float* __restrict__ Ct, float* __restrict__ rmv,
    int* __restrict__ rmj, int M)
{
    int bt = blockIdx.x;
    int lane = threadIdx.x;
    const float* row = Ct + (size_t)bt * M;

    float bv = 1e30f; int bj = 0;
    for (int c = 4 * lane; c < M; c += 256) {
        float4 v = *reinterpret_cast<const float4*>(row + c);
        if (v.x < bv) { bv = v.x; bj = c; }
        if (v.y < bv) { bv = v.y; bj = c + 1; }
        if (v.z < bv) { bv = v.z; bj = c + 2; }
        if (v.w < bv) { bv = v.w; bj = c + 3; }
    }
#pragma unroll
    for (int off = 1; off < 64; off <<= 1) {
        float ov = __shfl_xor(bv, off, 64);
        int oj = __shfl_xor(bj, off, 64);
        if (ov < bv || (ov == bv && oj < bj)) { bv = ov; bj = oj; }
    }
    if (lane == 0) { rmv[bt] = bv; rmj[bt] = bj; }
}

// ---------------------------------------------------------------------------
// Kernel 2: rectangular JV Hungarian, column-reduction init, single wave per
// batch. Bit-exact replication of the reference's e-maxx f64 arithmetic:
// every per-iteration "+= delta" chain is preserved op-for-op, but u-updates
// for tree rows accrue in per-lane REGISTERS (seeded with the phase-start
// value at mark-time) and are written back to LDS once per phase. The hot
// loop therefore has NO LDS writes: one prefetched LDS read (u[next row])
// and one prefetched global row load per iteration. Wave min uses a
// v_min_f64 DPP ladder (reduced costs, no NaN). L2 is warmed up-front so
// row loads are local-XCD L2 hits instead of cross-XCD Infinity-Cache hits.
// ---------------------------------------------------------------------------
__device__ __forceinline__ int sel4(int a0, int a1, int a2, int a3, int s) {
    return s == 0 ? a0 : (s == 1 ? a1 : (s == 2 ? a2 : a3));
}

// val = fmin(val, dpp_neighbor(val)); invalid lanes contribute +inf.
#define DPP_FMIN_STAGE(val, CTRL) do {                                        \
    long long _bits = __double_as_longlong(val);                              \
    int _lo = __builtin_amdgcn_update_dpp(0, (int)_bits,                      \
                                          CTRL, 0xf, 0xf, false);             \
    int _hi = __builtin_amdgcn_update_dpp(0x7FF00000, (int)(_bits >> 32),     \
                                          CTRL, 0xf, 0xf, false);             \
    double _o = __longlong_as_double(                                         \
        ((long long)_hi << 32) | (unsigned)_lo);                              \
    (val) = fmin((val), _o);                                                  \
} while (0)

__global__ __launch_bounds__(64) void hungarian_rect(
    const float* __restrict__ Ct, const float* __restrict__ boxc,
    const float* __restrict__ p_score, const float* __restrict__ t_score,
    const float* __restrict__ rmv, const int* __restrict__ rmj,
    float* __restrict__ out, int B, int M, int N)
{
    const double DINF = 1e30;
    int b = blockIdx.x;
    int lane = threadIdx.x;
    const float* C = Ct + (size_t)b * N * M;   // [N][M] rows contiguous

    __shared__ double u[257];                  // indexed by target 1..N
    __shared__ int ulist[257];                 // targets needing Dijkstra

    // ---- warm local-XCD L2 with this batch's cost rows (~192 KB) ----
    {
        int total = N * M;
        for (int off = 4 * lane; off < total; off += 256) {
            float4 w = *reinterpret_cast<const float4*>(C + off);
            asm volatile("" :: "v"(w.x), "v"(w.y), "v"(w.z), "v"(w.w));
        }
    }

    for (int k = lane; k < N; k += 64) u[k + 1] = (double)rmv[b * N + k];
    __syncthreads();

    const int j_base = 4 * lane + 1;           // first owned pred-col (1-based)
    double v0 = 0.0, v1 = 0.0, v2 = 0.0, v3 = 0.0;
    double m0, m1, m2, m3;
    int p0 = 0, p1 = 0, p2 = 0, p3 = 0;        // pred-col -> matched target
    int w0 = 0, w1 = 0, w2 = 0, w3 = 0;

    // preload row-argmins (slot q holds target q*64+lane)
    int rj0 = 0, rj1 = 0, rj2 = 0, rj3 = 0;
    {
        int base = b * N;
        if (lane < N)        rj0 = rmj[base + lane];
        if (64 + lane < N)   rj1 = rmj[base + 64 + lane];
        if (128 + lane < N)  rj2 = rmj[base + 128 + lane];
        if (192 + lane < N)  rj3 = rmj[base + 192 + lane];
    }

    // greedy pass: match t to its argmin column if that column is free
    int ucnt = 0;
    for (int t = 1; t <= N; ++t) {
        int q = (t - 1) >> 6, ln = (t - 1) & 63;
        int jm = __builtin_amdgcn_readlane(sel4(rj0, rj1, rj2, rj3, q), ln);
        int o = jm >> 2, s = jm & 3;
        int pv = __builtin_amdgcn_readlane(sel4(p0, p1, p2, p3, s), o);
        if (pv == 0) {
            if (lane == o) {
                if (s == 0) p0 = t;
                else if (s == 1) p1 = t;
                else if (s == 2) p2 = t;
                else p3 = t;
            }
        } else {
            if (lane == 0) ulist[ucnt] = t;
            ucnt++;
        }
    }
    __syncthreads();

    // Dijkstra phases for unmatched targets
    for (int uk = 0; uk < ucnt; ++uk) {
        int t = ulist[uk];
        m0 = DINF; m1 = DINF; m2 = DINF; m3 = DINF;
        int usedm = 0;
        double ur0 = 0, ur1 = 0, ur2 = 0, ur3 = 0;  // u of tree row per used slot
        int tg0 = 0, tg1 = 0, tg2 = 0, tg3 = 0;     // tree-row target per used slot
        int j0 = 0;                 // current pred-col (0 = virtual)
        int icur = t;               // row being scanned (p[j0]; p[0] = t)
        double ut = u[t];           // u[t], tracked in-register (wave-uniform)
        double u0 = ut;
        float4 r4 = *reinterpret_cast<const float4*>(
            C + (size_t)(t - 1) * M + 4 * lane);
        int jn;

        while (true) {
            // used[j0] = True; seed register copy of u[p[j0]] (phase-start val)
            if (j0 != 0 && ((j0 - 1) >> 2) == lane) {
                int s = (j0 - 1) & 3;
                usedm |= 1 << s;
                if (s == 0) { ur0 = u0; tg0 = icur; }
                else if (s == 1) { ur1 = u0; tg1 = icur; }
                else if (s == 2) { ur2 = u0; tg2 = icur; }
                else { ur3 = u0; tg3 = icur; }
            }

            // cur = (c - u) - v ; strict < update (free cols only)
            double a0 = DINF, a1 = DINF, a2d = DINF, a3 = DINF;
            if (!(usedm & 1)) {
                double cur = ((double)r4.x - u0) - v0;
                if (cur < m0) { m0 = cur; w0 = j0; }
                a0 = m0;
            }
            if (!(usedm & 2)) {
                double cur = ((double)r4.y - u0) - v1;
                if (cur < m1) { m1 = cur; w1 = j0; }
                a1 = m1;
            }
            if (!(usedm & 4)) {
                double cur = ((double)r4.z - u0) - v2;
                if (cur < m2) { m2 = cur; w2 = j0; }
                a2d = m2;
            }
            if (!(usedm & 8)) {
                double cur = ((double)r4.w - u0) - v3;
                if (cur < m3) { m3 = cur; w3 = j0; }
                a3 = m3;
            }

            // lane-local (min, smallest slot)
            double av = a0; int sa = 0;
            if (a1 < av)  { av = a1;  sa = 1; }
            if (a2d < av) { av = a2d; sa = 2; }
            if (a3 < av)  { av = a3;  sa = 3; }

            // wave min via v_min_f64 DPP ladder; lane 63 holds the result
            double wv_ = av;
            DPP_FMIN_STAGE(wv_, 0x111);   // row_shr:1
            DPP_FMIN_STAGE(wv_, 0x112);   // row_shr:2
            DPP_FMIN_STAGE(wv_, 0x114);   // row_shr:4
            DPP_FMIN_STAGE(wv_, 0x118);   // row_shr:8
            DPP_FMIN_STAGE(wv_, 0x142);   // row_bcast:15
            DPP_FMIN_STAGE(wv_, 0x143);   // row_bcast:31
            long long wb = __double_as_longlong(wv_);
            int wlo = __builtin_amdgcn_readlane((int)wb, 63);
            int whi = __builtin_amdgcn_readlane((int)(wb >> 32), 63);
            double delta = __longlong_as_double(
                ((long long)whi << 32) | (unsigned)wlo);

            unsigned long long ball = __ballot(av == delta);
            int owner = __builtin_ctzll(ball);   // lowest lane = smallest col
            int pk = (j_base + sa) | (sel4(p0, p1, p2, p3, sa) << 9);
            pk = __builtin_amdgcn_readlane(pk, owner);
            int jn_ = pk & 511, pjn = pk >> 9;

            // early reads for next iteration (u has NO writes during a phase)
            int nxt = (pjn > 0) ? pjn : t;
            double u_next = u[nxt];
            float4 r4n = *reinterpret_cast<const float4*>(
                C + (size_t)(nxt - 1) * M + 4 * lane);

            // exact per-iteration updates (register-resident)
            if (usedm & 1) { ur0 += delta; v0 -= delta; } else m0 -= delta;
            if (usedm & 2) { ur1 += delta; v1 -= delta; } else m1 -= delta;
            if (usedm & 4) { ur2 += delta; v2 -= delta; } else m2 -= delta;
            if (usedm & 8) { ur3 += delta; v3 -= delta; } else m3 -= delta;
            ut += delta;                       // virtual column: p[0] = t

            jn = jn_;
            if (pjn == 0) break;
            j0 = jn_; u0 = u_next; r4 = r4n; icur = pjn;
        }

        // phase-end u writeback (distinct targets per used column: race-free)
        if (usedm & 1) u[tg0] = ur0;
        if (usedm & 2) u[tg1] = ur1;
        if (usedm & 4) u[tg2] = ur2;
        if (usedm & 8) u[tg3] = ur3;
        if (lane == 0) u[t] = ut;

        // augment: stream p[j_k] = p_old[j_{k+1}] one step behind the
        // traversal; one readlane per step (packed way|p).
        int jj = jn, prev = 0;
        while (true) {
            int idx = jj - 1;
            int o = idx >> 2, s = idx & 3;
            int packv = sel4(w0, w1, w2, w3, s) |
                        (sel4(p0, p1, p2, p3, s) << 9);
            packv = __builtin_amdgcn_readlane(packv, o);
            int wv = packv & 511, pold = packv >> 9;
            if (prev != 0) {
                int pi = prev - 1;
                if (lane == (pi >> 2)) {
                    int sp = pi & 3;
                    if (sp == 0) p0 = pold;
                    else if (sp == 1) p1 = pold;
                    else if (sp == 2) p2 = pold;
                    else p3 = pold;
                }
            }
            if (wv == 0) {
                if (lane == o) {
                    if (s == 0) p0 = t;
                    else if (s == 1) p1 = t;
                    else if (s == 2) p2 = t;
                    else p3 = t;
                }
                break;
            }
            prev = jj; jj = wv;
        }
    }

    // matched sums over real pairs: pred-col j (owned) matched to target p[j]
    double sm = 0.0, ss = 0.0, sb = 0.0;
#pragma unroll
    for (int s = 0; s < 4; ++s) {
        int pt = sel4(p0, p1, p2, p3, s);
        if (pt != 0) {
            int r = j_base + s - 1;   // pred index
            int c = pt - 1;           // target index
            sm += (double)C[(size_t)c * M + r];
            sb += (double)boxc[((size_t)b * M + r) * N + c];
            ss += (double)fmaxf(0.0f, t_score[b * N + c] - p_score[b * M + r]);
        }
    }
#pragma unroll
    for (int off = 1; off < 64; off <<= 1) {
        sm += __shfl_xor(sm, off, 64);
        ss += __shfl_xor(ss, off, 64);
        sb += __shfl_xor(sb, off, 64);
    }
    if (lane == 0) {
        out[0 * B + b] = (float)(sm / N);
        out[1 * B + b] = (float)(ss / N);
        out[2 * B + b] = (float)(sb / N);
    }
}

extern "C" void kernel_launch(void* const* d_in, const int* in_sizes, int n_in,
                              void* d_out, int out_size, void* d_ws, size_t ws_size,
                              hipStream_t stream) {
    int B = out_size / 3;                 // out is [3, B]
    int M = in_sizes[1] / B;              // pred_score [B, M]
    int N = in_sizes[3] / B;              // target_score [B, N]

    const float* p_box   = (const float*)d_in[0];
    const float* p_score = (const float*)d_in[1];
    const float* t_box   = (const float*)d_in[2];
    const float* t_score = (const float*)d_in[3];
    float* out = (float*)d_out;

    float* Ct   = (float*)d_ws;                       // [B, N, M]
    float* boxc = Ct + (size_t)B * N * M;             // [B, M, N]
    float* rmv  = boxc + (size_t)B * M * N;           // [B, N]
    int*   rmj  = (int*)(rmv + (size_t)B * N);        // [B, N]

    int total = B * M * N;
    cost_kernel<<<(total + 255) / 256, 256, 0, stream>>>(
        p_box, p_score, t_box, t_score, Ct, boxc, B, M, N);
    rowmin_kernel<<<B * N, 64, 0, stream>>>(Ct, rmv, rmj, M);
    hungarian_rect<<<B, 64, 0, stream>>>(
        Ct, boxc, p_score, t_score, rmv, rmj, out, B, M, N);
}

// Round 7
// 610.771 us; speedup vs baseline: 34.5104x; 1.1403x over previous
//
#include <hip/hip_runtime.h>
#include <cmath>

#define MAXV 8

// ---------------------------------------------------------------------------
// Kernel 1: cost matrices for the RECTANGULAR problem (no padding).
// One thread per (b, n, m), m fastest. Writes:
//   Ct[b][n][m]  = score_cost + giou_cost   (transposed cost, coalesced rows)
//   boxc[b][m][n] = giou_cost
// Math mirrors the reference f32 op order exactly.
// ---------------------------------------------------------------------------
__global__ __launch_bounds__(256) void cost_kernel(
    const float* __restrict__ p_box, const float* __restrict__ p_score,
    const float* __restrict__ t_box, const float* __restrict__ t_score,
    float* __restrict__ Ct, float* __restrict__ boxc,
    int B, int M, int N)
{
    int g = blockIdx.x * 256 + threadIdx.x;
    int total = B * M * N;
    if (g >= total) return;
    int b = g / (M * N);
    int rem = g - b * M * N;
    int n = rem / M;
    int m = rem - n * M;

    const float* bp = p_box + ((size_t)b * M + m) * 5;
    const float* bt = t_box + ((size_t)b * N + n) * 5;
    float pcx = bp[0], pcy = bp[1], pw = bp[2], ph = bp[3], pth = bp[4];
    float tcx = bt[0], tcy = bt[1], tw = bt[2], th = bt[3], tth = bt[4];

    float pc = cosf(pth), ps = sinf(pth);
    float tc = cosf(tth), ts = sinf(tth);

    const float DX[4] = {-0.5f, 0.5f, 0.5f, -0.5f};
    const float DY[4] = {-0.5f, -0.5f, 0.5f, 0.5f};
    float cpx[4], cpy[4], ctx[4], cty[4];
#pragma unroll
    for (int k = 0; k < 4; k++) {
        float dx = DX[k] * pw, dy = DY[k] * ph;
        cpx[k] = pcx + dx * pc - dy * ps;
        cpy[k] = pcy + dx * ps + dy * pc;
        float dx2 = DX[k] * tw, dy2 = DY[k] * th;
        ctx[k] = tcx + dx2 * tc - dy2 * ts;
        cty[k] = tcy + dx2 * ts + dy2 * tc;
    }

    float px[MAXV], py[MAXV];
#pragma unroll
    for (int k = 0; k < MAXV; k++) {
        px[k] = (k < 4) ? cpx[k] : 0.0f;
        py[k] = (k < 4) ? cpy[k] : 0.0f;
    }
    int cnt = 4;

#pragma unroll
    for (int e = 0; e < 4; e++) {
        float ax = ctx[e], ay = cty[e];
        float bx2 = ctx[(e + 1) & 3], by2 = cty[(e + 1) & 3];
        float dx = bx2 - ax, dy = by2 - ay;
        float qx[MAXV], qy[MAXV];
#pragma unroll
        for (int k = 0; k < MAXV; k++) { qx[k] = 0.0f; qy[k] = 0.0f; }
        int nc = 0;
#pragma unroll
        for (int i = 0; i < MAXV; i++) {
            if (i < cnt) {
                bool wrap = !(i + 1 < cnt);
                float nx = wrap ? px[0] : px[(i + 1) & 7];
                float ny = wrap ? py[0] : py[(i + 1) & 7];
                float sc = dx * (py[i] - ay) - dy * (px[i] - ax);
                float sn = dx * (ny - ay) - dy * (nx - ax);
                bool inc = (sc >= 0.0f), inn = (sn >= 0.0f);
                float den = sc - sn;
                if (!(fabsf(den) > 1e-9f)) den = 1e-9f;
                float t = sc / den;
                float ix = px[i] + t * (nx - px[i]);
                float iy = py[i] + t * (ny - py[i]);
                if (inc) {
                    if (nc < MAXV) { qx[nc] = px[i]; qy[nc] = py[i]; }
                    nc++;
                }
                if (inc != inn) {
                    if (nc < MAXV) { qx[nc] = ix; qy[nc] = iy; }
                    nc++;
                }
            }
        }
        cnt = (nc > MAXV) ? MAXV : nc;
#pragma unroll
        for (int k = 0; k < MAXV; k++) {
            px[k] = (k < cnt) ? qx[k] : 0.0f;
            py[k] = (k < cnt) ? qy[k] : 0.0f;
        }
    }

    float a2 = 0.0f;
#pragma unroll
    for (int i = 0; i < MAXV; i++) {
        if (i < cnt) {
            bool wrap = !(i + 1 < cnt);
            float nx = wrap ? px[0] : px[(i + 1) & 7];
            float ny = wrap ? py[0] : py[(i + 1) & 7];
            a2 += px[i] * ny - nx * py[i];
        }
    }
    float inter = 0.5f * fabsf(a2);

    float uni = tw * th + pw * ph - inter;

    float xmin = ctx[0], xmax = ctx[0], ymin = cty[0], ymax = cty[0];
#pragma unroll
    for (int k = 1; k < 4; k++) {
        xmin = fminf(xmin, ctx[k]); xmax = fmaxf(xmax, ctx[k]);
        ymin = fminf(ymin, cty[k]); ymax = fmaxf(ymax, cty[k]);
    }
#pragma unroll
    for (int k = 0; k < 4; k++) {
        xmin = fminf(xmin, cpx[k]); xmax = fmaxf(xmax, cpx[k]);
        ymin = fminf(ymin, cpy[k]); ymax = fmaxf(ymax, cpy[k]);
    }
    float enc = (xmax - xmin) * (ymax - ymin);

    float giou = inter / uni - (enc - uni) / enc;
    float bc = 1.0f - giou;
    float scst = fmaxf(0.0f, t_score[b * N + n] - p_score[b * M + m]);

    Ct[((size_t)b * N + n) * M + m] = scst + bc;
    boxc[((size_t)b * M + m) * N + n] = bc;
}

// ---------------------------------------------------------------------------
// Kernel 1.5: per-target-row (min, first argmin) over the M pred columns.
// ---------------------------------------------------------------------------
__global__ __launch_bounds__(64) void rowmin_kernel(
    const float* __restrict__ Ct, float* __restrict__ rmv,
    int* __restrict__ rmj, int M)
{
    int bt = blockIdx.x;
    int lane = threadIdx.x;
    const float* row = Ct + (size_t)bt * M;

    float bv = 1e30f; int bj = 0;
    for (int c = 4 * lane; c < M; c += 256) {
        float4 v = *reinterpret_cast<const float4*>(row + c);
        if (v.x < bv) { bv = v.x; bj = c; }
        if (v.y < bv) { bv = v.y; bj = c + 1; }
        if (v.z < bv) { bv = v.z; bj = c + 2; }
        if (v.w < bv) { bv = v.w; bj = c + 3; }
    }
#pragma unroll
    for (int off = 1; off < 64; off <<= 1) {
        float ov = __shfl_xor(bv, off, 64);
        int oj = __shfl_xor(bj, off, 64);
        if (ov < bv || (ov == bv && oj < bj)) { bv = ov; bj = oj; }
    }
    if (lane == 0) { rmv[bt] = bv; rmj[bt] = bj; }
}

// ---------------------------------------------------------------------------
// Kernel 2: rectangular JV Hungarian, column-reduction init, single wave per
// batch. Solver arithmetic in f32 (costs are f32; an f32 comparison flip
// requires a ~2e-7 near-tie — measure-~0 for this data, and any flip moves
// the outputs by <<threshold). Hot loop: no LDS writes (deferred-u in
// registers, written back once per phase), one prefetched ds_read_b32 +
// one prefetched global row load per iteration, v_min_f32 DPP ladder for
// the wave argmin, readlane/ballot for broadcasts. L2 warmed up-front.
// ---------------------------------------------------------------------------
__device__ __forceinline__ int sel4(int a0, int a1, int a2, int a3, int s) {
    return s == 0 ? a0 : (s == 1 ? a1 : (s == 2 ? a2 : a3));
}

// val = fminf(val, dpp_neighbor(val)); invalid lanes contribute +inf.
#define DPP_FMIN32_STAGE(val, CTRL) do {                                      \
    int _o = __builtin_amdgcn_update_dpp(0x7F800000,                          \
                 __float_as_int(val), CTRL, 0xf, 0xf, false);                 \
    (val) = fminf((val), __int_as_float(_o));                                 \
} while (0)

__global__ __launch_bounds__(64) void hungarian_rect(
    const float* __restrict__ Ct, const float* __restrict__ boxc,
    const float* __restrict__ p_score, const float* __restrict__ t_score,
    const float* __restrict__ rmv, const int* __restrict__ rmj,
    float* __restrict__ out, int B, int M, int N)
{
    const float FINF = 1e30f;
    int b = blockIdx.x;
    int lane = threadIdx.x;
    const float* C = Ct + (size_t)b * N * M;   // [N][M] rows contiguous

    __shared__ float u[257];                   // indexed by target 1..N
    __shared__ int ulist[257];                 // targets needing Dijkstra

    // ---- warm local-XCD L2 with this batch's cost rows (~192 KB) ----
    {
        int total = N * M;
        for (int off = 4 * lane; off < total; off += 256) {
            float4 w = *reinterpret_cast<const float4*>(C + off);
            asm volatile("" :: "v"(w.x), "v"(w.y), "v"(w.z), "v"(w.w));
        }
    }

    for (int k = lane; k < N; k += 64) u[k + 1] = rmv[b * N + k];
    __syncthreads();

    const int j_base = 4 * lane + 1;           // first owned pred-col (1-based)
    float v0 = 0.0f, v1 = 0.0f, v2 = 0.0f, v3 = 0.0f;
    float m0, m1, m2, m3;
    int p0 = 0, p1 = 0, p2 = 0, p3 = 0;        // pred-col -> matched target
    int w0 = 0, w1 = 0, w2 = 0, w3 = 0;

    // preload row-argmins (slot q holds target q*64+lane)
    int rj0 = 0, rj1 = 0, rj2 = 0, rj3 = 0;
    {
        int base = b * N;
        if (lane < N)        rj0 = rmj[base + lane];
        if (64 + lane < N)   rj1 = rmj[base + 64 + lane];
        if (128 + lane < N)  rj2 = rmj[base + 128 + lane];
        if (192 + lane < N)  rj3 = rmj[base + 192 + lane];
    }

    // greedy pass: match t to its argmin column if that column is free
    int ucnt = 0;
    for (int t = 1; t <= N; ++t) {
        int q = (t - 1) >> 6, ln = (t - 1) & 63;
        int jm = __builtin_amdgcn_readlane(sel4(rj0, rj1, rj2, rj3, q), ln);
        int o = jm >> 2, s = jm & 3;
        int pv = __builtin_amdgcn_readlane(sel4(p0, p1, p2, p3, s), o);
        if (pv == 0) {
            if (lane == o) {
                if (s == 0) p0 = t;
                else if (s == 1) p1 = t;
                else if (s == 2) p2 = t;
                else p3 = t;
            }
        } else {
            if (lane == 0) ulist[ucnt] = t;
            ucnt++;
        }
    }
    __syncthreads();

    // Dijkstra phases for unmatched targets
    for (int uk = 0; uk < ucnt; ++uk) {
        int t = ulist[uk];
        m0 = FINF; m1 = FINF; m2 = FINF; m3 = FINF;
        int usedm = 0;
        float ur0 = 0, ur1 = 0, ur2 = 0, ur3 = 0;   // u of tree row per slot
        int tg0 = 0, tg1 = 0, tg2 = 0, tg3 = 0;     // tree-row target per slot
        int j0 = 0;                 // current pred-col (0 = virtual)
        int icur = t;               // row being scanned (p[j0]; p[0] = t)
        float ut = u[t];            // u[t], tracked in-register (wave-uniform)
        float u0 = ut;
        float4 r4 = *reinterpret_cast<const float4*>(
            C + (size_t)(t - 1) * M + 4 * lane);
        int jn;

        while (true) {
            // used[j0] = True; seed register copy of u[p[j0]]
            if (j0 != 0 && ((j0 - 1) >> 2) == lane) {
                int s = (j0 - 1) & 3;
                usedm |= 1 << s;
                if (s == 0) { ur0 = u0; tg0 = icur; }
                else if (s == 1) { ur1 = u0; tg1 = icur; }
                else if (s == 2) { ur2 = u0; tg2 = icur; }
                else { ur3 = u0; tg3 = icur; }
            }

            // cur = (c - u) - v ; strict < update (free cols only)
            float a0 = FINF, a1 = FINF, a2f = FINF, a3 = FINF;
            if (!(usedm & 1)) {
                float cur = (r4.x - u0) - v0;
                if (cur < m0) { m0 = cur; w0 = j0; }
                a0 = m0;
            }
            if (!(usedm & 2)) {
                float cur = (r4.y - u0) - v1;
                if (cur < m1) { m1 = cur; w1 = j0; }
                a1 = m1;
            }
            if (!(usedm & 4)) {
                float cur = (r4.z - u0) - v2;
                if (cur < m2) { m2 = cur; w2 = j0; }
                a2f = m2;
            }
            if (!(usedm & 8)) {
                float cur = (r4.w - u0) - v3;
                if (cur < m3) { m3 = cur; w3 = j0; }
                a3 = m3;
            }

            // lane-local (min, smallest slot)
            float av = a0; int sa = 0;
            if (a1 < av)  { av = a1;  sa = 1; }
            if (a2f < av) { av = a2f; sa = 2; }
            if (a3 < av)  { av = a3;  sa = 3; }

            // wave min via v_min_f32 DPP ladder; lane 63 holds the result
            float wv_ = av;
            DPP_FMIN32_STAGE(wv_, 0x111);   // row_shr:1
            DPP_FMIN32_STAGE(wv_, 0x112);   // row_shr:2
            DPP_FMIN32_STAGE(wv_, 0x114);   // row_shr:4
            DPP_FMIN32_STAGE(wv_, 0x118);   // row_shr:8
            DPP_FMIN32_STAGE(wv_, 0x142);   // row_bcast:15
            DPP_FMIN32_STAGE(wv_, 0x143);   // row_bcast:31
            float delta = __int_as_float(
                __builtin_amdgcn_readlane(__float_as_int(wv_), 63));

            unsigned long long ball = __ballot(av == delta);
            int owner = __builtin_ctzll(ball);   // lowest lane = smallest col
            int pk = (j_base + sa) | (sel4(p0, p1, p2, p3, sa) << 9);
            pk = __builtin_amdgcn_readlane(pk, owner);
            int jn_ = pk & 511, pjn = pk >> 9;

            // early reads for next iteration (u has NO writes during a phase)
            int nxt = (pjn > 0) ? pjn : t;
            float u_next = u[nxt];
            float4 r4n = *reinterpret_cast<const float4*>(
                C + (size_t)(nxt - 1) * M + 4 * lane);

            // per-iteration dual/minv updates (register-resident)
            if (usedm & 1) { ur0 += delta; v0 -= delta; } else m0 -= delta;
            if (usedm & 2) { ur1 += delta; v1 -= delta; } else m1 -= delta;
            if (usedm & 4) { ur2 += delta; v2 -= delta; } else m2 -= delta;
            if (usedm & 8) { ur3 += delta; v3 -= delta; } else m3 -= delta;
            ut += delta;                       // virtual column: p[0] = t

            jn = jn_;
            if (pjn == 0) break;
            j0 = jn_; u0 = u_next; r4 = r4n; icur = pjn;
        }

        // phase-end u writeback (distinct targets per used column: race-free)
        if (usedm & 1) u[tg0] = ur0;
        if (usedm & 2) u[tg1] = ur1;
        if (usedm & 4) u[tg2] = ur2;
        if (usedm & 8) u[tg3] = ur3;
        if (lane == 0) u[t] = ut;

        // augment: stream p[j_k] = p_old[j_{k+1}] one step behind the
        // traversal; one readlane per step (packed way|p).
        int jj = jn, prev = 0;
        while (true) {
            int idx = jj - 1;
            int o = idx >> 2, s = idx & 3;
            int packv = sel4(w0, w1, w2, w3, s) |
                        (sel4(p0, p1, p2, p3, s) << 9);
            packv = __builtin_amdgcn_readlane(packv, o);
            int wv = packv & 511, pold = packv >> 9;
            if (prev != 0) {
                int pi = prev - 1;
                if (lane == (pi >> 2)) {
                    int sp = pi & 3;
                    if (sp == 0) p0 = pold;
                    else if (sp == 1) p1 = pold;
                    else if (sp == 2) p2 = pold;
                    else p3 = pold;
                }
            }
            if (wv == 0) {
                if (lane == o) {
                    if (s == 0) p0 = t;
                    else if (s == 1) p1 = t;
                    else if (s == 2) p2 = t;
                    else p3 = t;
                }
                break;
            }
            prev = jj; jj = wv;
        }
    }

    // matched sums over real pairs: pred-col j (owned) matched to target p[j]
    double sm = 0.0, ss = 0.0, sb = 0.0;
#pragma unroll
    for (int s = 0; s < 4; ++s) {
        int pt = sel4(p0, p1, p2, p3, s);
        if (pt != 0) {
            int r = j_base + s - 1;   // pred index
            int c = pt - 1;           // target index
            sm += (double)C[(size_t)c * M + r];
            sb += (double)boxc[((size_t)b * M + r) * N + c];
            ss += (double)fmaxf(0.0f, t_score[b * N + c] - p_score[b * M + r]);
        }
    }
#pragma unroll
    for (int off = 1; off < 64; off <<= 1) {
        sm += __shfl_xor(sm, off, 64);
        ss += __shfl_xor(ss, off, 64);
        sb += __shfl_xor(sb, off, 64);
    }
    if (lane == 0) {
        out[0 * B + b] = (float)(sm / N);
        out[1 * B + b] = (float)(ss / N);
        out[2 * B + b] = (float)(sb / N);
    }
}

extern "C" void kernel_launch(void* const* d_in, const int* in_sizes, int n_in,
                              void* d_out, int out_size, void* d_ws, size_t ws_size,
                              hipStream_t stream) {
    int B = out_size / 3;                 // out is [3, B]
    int M = in_sizes[1] / B;              // pred_score [B, M]
    int N = in_sizes[3] / B;              // target_score [B, N]

    const float* p_box   = (const float*)d_in[0];
    const float* p_score = (const float*)d_in[1];
    const float* t_box   = (const float*)d_in[2];
    const float* t_score = (const float*)d_in[3];
    float* out = (float*)d_out;

    float* Ct   = (float*)d_ws;                       // [B, N, M]
    float* boxc = Ct + (size_t)B * N * M;             // [B, M, N]
    float* rmv  = boxc + (size_t)B * M * N;           // [B, N]
    int*   rmj  = (int*)(rmv + (size_t)B * N);        // [B, N]

    int total = B * M * N;
    cost_kernel<<<(total + 255) / 256, 256, 0, stream>>>(
        p_box, p_score, t_box, t_score, Ct, boxc, B, M, N);
    rowmin_kernel<<<B * N, 64, 0, stream>>>(Ct, rmv, rmj, M);
    hungarian_rect<<<B, 64, 0, stream>>>(
        Ct, boxc, p_score, t_score, rmv, rmj, out, B, M, N);
}

// Round 8
// 580.849 us; speedup vs baseline: 36.2882x; 1.0515x over previous
//
#include <hip/hip_runtime.h>
#include <cmath>

#define MAXV 8

// ---------------------------------------------------------------------------
// Kernel 1: cost matrices for the RECTANGULAR problem (no padding).
// One thread per (b, n, m), m fastest. Writes:
//   Ct[b][n][m]  = score_cost + giou_cost   (transposed cost, coalesced rows)
//   boxc[b][m][n] = giou_cost
// Math mirrors the reference f32 op order exactly.
// ---------------------------------------------------------------------------
__global__ __launch_bounds__(256) void cost_kernel(
    const float* __restrict__ p_box, const float* __restrict__ p_score,
    const float* __restrict__ t_box, const float* __restrict__ t_score,
    float* __restrict__ Ct, float* __restrict__ boxc,
    int B, int M, int N)
{
    int g = blockIdx.x * 256 + threadIdx.x;
    int total = B * M * N;
    if (g >= total) return;
    int b = g / (M * N);
    int rem = g - b * M * N;
    int n = rem / M;
    int m = rem - n * M;

    const float* bp = p_box + ((size_t)b * M + m) * 5;
    const float* bt = t_box + ((size_t)b * N + n) * 5;
    float pcx = bp[0], pcy = bp[1], pw = bp[2], ph = bp[3], pth = bp[4];
    float tcx = bt[0], tcy = bt[1], tw = bt[2], th = bt[3], tth = bt[4];

    float pc = cosf(pth), ps = sinf(pth);
    float tc = cosf(tth), ts = sinf(tth);

    const float DX[4] = {-0.5f, 0.5f, 0.5f, -0.5f};
    const float DY[4] = {-0.5f, -0.5f, 0.5f, 0.5f};
    float cpx[4], cpy[4], ctx[4], cty[4];
#pragma unroll
    for (int k = 0; k < 4; k++) {
        float dx = DX[k] * pw, dy = DY[k] * ph;
        cpx[k] = pcx + dx * pc - dy * ps;
        cpy[k] = pcy + dx * ps + dy * pc;
        float dx2 = DX[k] * tw, dy2 = DY[k] * th;
        ctx[k] = tcx + dx2 * tc - dy2 * ts;
        cty[k] = tcy + dx2 * ts + dy2 * tc;
    }

    float px[MAXV], py[MAXV];
#pragma unroll
    for (int k = 0; k < MAXV; k++) {
        px[k] = (k < 4) ? cpx[k] : 0.0f;
        py[k] = (k < 4) ? cpy[k] : 0.0f;
    }
    int cnt = 4;

#pragma unroll
    for (int e = 0; e < 4; e++) {
        float ax = ctx[e], ay = cty[e];
        float bx2 = ctx[(e + 1) & 3], by2 = cty[(e + 1) & 3];
        float dx = bx2 - ax, dy = by2 - ay;
        float qx[MAXV], qy[MAXV];
#pragma unroll
        for (int k = 0; k < MAXV; k++) { qx[k] = 0.0f; qy[k] = 0.0f; }
        int nc = 0;
#pragma unroll
        for (int i = 0; i < MAXV; i++) {
            if (i < cnt) {
                bool wrap = !(i + 1 < cnt);
                float nx = wrap ? px[0] : px[(i + 1) & 7];
                float ny = wrap ? py[0] : py[(i + 1) & 7];
                float sc = dx * (py[i] - ay) - dy * (px[i] - ax);
                float sn = dx * (ny - ay) - dy * (nx - ax);
                bool inc = (sc >= 0.0f), inn = (sn >= 0.0f);
                float den = sc - sn;
                if (!(fabsf(den) > 1e-9f)) den = 1e-9f;
                float t = sc / den;
                float ix = px[i] + t * (nx - px[i]);
                float iy = py[i] + t * (ny - py[i]);
                if (inc) {
                    if (nc < MAXV) { qx[nc] = px[i]; qy[nc] = py[i]; }
                    nc++;
                }
                if (inc != inn) {
                    if (nc < MAXV) { qx[nc] = ix; qy[nc] = iy; }
                    nc++;
                }
            }
        }
        cnt = (nc > MAXV) ? MAXV : nc;
#pragma unroll
        for (int k = 0; k < MAXV; k++) {
            px[k] = (k < cnt) ? qx[k] : 0.0f;
            py[k] = (k < cnt) ? qy[k] : 0.0f;
        }
    }

    float a2 = 0.0f;
#pragma unroll
    for (int i = 0; i < MAXV; i++) {
        if (i < cnt) {
            bool wrap = !(i + 1 < cnt);
            float nx = wrap ? px[0] : px[(i + 1) & 7];
            float ny = wrap ? py[0] : py[(i + 1) & 7];
            a2 += px[i] * ny - nx * py[i];
        }
    }
    float inter = 0.5f * fabsf(a2);

    float uni = tw * th + pw * ph - inter;

    float xmin = ctx[0], xmax = ctx[0], ymin = cty[0], ymax = cty[0];
#pragma unroll
    for (int k = 1; k < 4; k++) {
        xmin = fminf(xmin, ctx[k]); xmax = fmaxf(xmax, ctx[k]);
        ymin = fminf(ymin, cty[k]); ymax = fmaxf(ymax, cty[k]);
    }
#pragma unroll
    for (int k = 0; k < 4; k++) {
        xmin = fminf(xmin, cpx[k]); xmax = fmaxf(xmax, cpx[k]);
        ymin = fminf(ymin, cpy[k]); ymax = fmaxf(ymax, cpy[k]);
    }
    float enc = (xmax - xmin) * (ymax - ymin);

    float giou = inter / uni - (enc - uni) / enc;
    float bc = 1.0f - giou;
    float scst = fmaxf(0.0f, t_score[b * N + n] - p_score[b * M + m]);

    Ct[((size_t)b * N + n) * M + m] = scst + bc;
    boxc[((size_t)b * M + m) * N + n] = bc;
}

// ---------------------------------------------------------------------------
// Kernel 1.5: per-target-row (min, first argmin) over the M pred columns.
// ---------------------------------------------------------------------------
__global__ __launch_bounds__(64) void rowmin_kernel(
    const float* __restrict__ Ct, float* __restrict__ rmv,
    int* __restrict__ rmj, int M)
{
    int bt = blockIdx.x;
    int lane = threadIdx.x;
    const float* row = Ct + (size_t)bt * M;

    float bv = 1e30f; int bj = 0;
    for (int c = 4 * lane; c < M; c += 256) {
        float4 v = *reinterpret_cast<const float4*>(row + c);
        if (v.x < bv) { bv = v.x; bj = c; }
        if (v.y < bv) { bv = v.y; bj = c + 1; }
        if (v.z < bv) { bv = v.z; bj = c + 2; }
        if (v.w < bv) { bv = v.w; bj = c + 3; }
    }
#pragma unroll
    for (int off = 1; off < 64; off <<= 1) {
        float ov = __shfl_xor(bv, off, 64);
        int oj = __shfl_xor(bj, off, 64);
        if (ov < bv || (ov == bv && oj < bj)) { bv = ov; bj = oj; }
    }
    if (lane == 0) { rmv[bt] = bv; rmj[bt] = bj; }
}

// ---------------------------------------------------------------------------
// Kernel 2: rectangular JV Hungarian, single wave per batch, three stages:
//  (1) column-reduction init (u=rowmin) + greedy matching,
//  (2) augmenting row reduction (JV ARR / auction-style): per unmatched row,
//      (min1,min2) of the reduced row via a paired DPP ladder; u[i]=min2;
//      strictly-best column is taken (v[j1] -= gap, displacing its owner,
//      chain continues). Exact ties on occupied cols (or step cap) defer the
//      row to the Dijkstra list. Maintains dual feasibility + slackness at
//      every step, so the result stays the exact unique optimum.
//  (3) e-maxx Dijkstra phases for the few deferred rows (deferred-u in
//      registers, no LDS writes in the hot loop, v_min_f32 DPP argmin).
// ---------------------------------------------------------------------------
__device__ __forceinline__ int sel4(int a0, int a1, int a2, int a3, int s) {
    return s == 0 ? a0 : (s == 1 ? a1 : (s == 2 ? a2 : a3));
}

// val = fminf(val, dpp_neighbor(val)); invalid lanes contribute +inf.
#define DPP_FMIN32_STAGE(val, CTRL) do {                                      \
    int _o = __builtin_amdgcn_update_dpp(0x7F800000,                          \
                 __float_as_int(val), CTRL, 0xf, 0xf, false);                 \
    (val) = fminf((val), __int_as_float(_o));                                 \
} while (0)

// paired (min1,min2) reduction stage; disjoint lane-set combine:
// m2' = min(max(m1a,m1b), min(m2a,m2b)); m1' = min(m1a,m1b).
#define DPP_PAIR_STAGE(g1, g2, CTRL) do {                                     \
    int _b1 = __builtin_amdgcn_update_dpp(0x7F800000,                         \
                  __float_as_int(g1), CTRL, 0xf, 0xf, false);                 \
    int _b2 = __builtin_amdgcn_update_dpp(0x7F800000,                         \
                  __float_as_int(g2), CTRL, 0xf, 0xf, false);                 \
    float _o1 = __int_as_float(_b1), _o2 = __int_as_float(_b2);               \
    float _n2 = fminf(fmaxf((g1), _o1), fminf((g2), _o2));                    \
    (g1) = fminf((g1), _o1);                                                  \
    (g2) = _n2;                                                               \
} while (0)

__global__ __launch_bounds__(64) void hungarian_rect(
    const float* __restrict__ Ct, const float* __restrict__ boxc,
    const float* __restrict__ p_score, const float* __restrict__ t_score,
    const float* __restrict__ rmv, const int* __restrict__ rmj,
    float* __restrict__ out, int B, int M, int N)
{
    const float FINF = 1e30f;
    int b = blockIdx.x;
    int lane = threadIdx.x;
    const float* C = Ct + (size_t)b * N * M;   // [N][M] rows contiguous

    __shared__ float u[257];                   // indexed by target 1..N
    __shared__ int ulist[257];                 // greedy-unmatched targets
    __shared__ int dlist[257];                 // targets needing Dijkstra

    // ---- warm local-XCD L2 with this batch's cost rows (~192 KB) ----
    {
        int total = N * M;
        for (int off = 4 * lane; off < total; off += 256) {
            float4 w = *reinterpret_cast<const float4*>(C + off);
            asm volatile("" :: "v"(w.x), "v"(w.y), "v"(w.z), "v"(w.w));
        }
    }

    for (int k = lane; k < N; k += 64) u[k + 1] = rmv[b * N + k];
    __syncthreads();

    const int j_base = 4 * lane + 1;           // first owned pred-col (1-based)
    float v0 = 0.0f, v1 = 0.0f, v2 = 0.0f, v3 = 0.0f;
    float m0, m1, m2, m3;
    int p0 = 0, p1 = 0, p2 = 0, p3 = 0;        // pred-col -> matched target
    int w0 = 0, w1 = 0, w2 = 0, w3 = 0;

    // preload row-argmins (slot q holds target q*64+lane)
    int rj0 = 0, rj1 = 0, rj2 = 0, rj3 = 0;
    {
        int base = b * N;
        if (lane < N)        rj0 = rmj[base + lane];
        if (64 + lane < N)   rj1 = rmj[base + 64 + lane];
        if (128 + lane < N)  rj2 = rmj[base + 128 + lane];
        if (192 + lane < N)  rj3 = rmj[base + 192 + lane];
    }

    // ---- stage 1: greedy pass (match t to its argmin column if free) ----
    int ucnt = 0;
    for (int t = 1; t <= N; ++t) {
        int q = (t - 1) >> 6, ln = (t - 1) & 63;
        int jm = __builtin_amdgcn_readlane(sel4(rj0, rj1, rj2, rj3, q), ln);
        int o = jm >> 2, s = jm & 3;
        int pv = __builtin_amdgcn_readlane(sel4(p0, p1, p2, p3, s), o);
        if (pv == 0) {
            if (lane == o) {
                if (s == 0) p0 = t;
                else if (s == 1) p1 = t;
                else if (s == 2) p2 = t;
                else p3 = t;
            }
        } else {
            if (lane == 0) ulist[ucnt] = t;
            ucnt++;
        }
    }
    __syncthreads();

    // ---- stage 2: augmenting row reduction (exact JV ARR) ----
    int dcnt = 0;
    {
        int pi = 0, steps = 0;
        int i = (pi < ucnt) ? ulist[pi++] : 0;
        while (i != 0) {
            ++steps;
            if (steps > 2048) {          // safety cap: dump rest to Dijkstra
                if (lane == 0) dlist[dcnt] = i;
                dcnt++;
                while (pi < ucnt) {
                    if (lane == 0) dlist[dcnt] = ulist[pi];
                    dcnt++; pi++;
                }
                break;
            }
            float4 r4 = *reinterpret_cast<const float4*>(
                C + (size_t)(i - 1) * M + 4 * lane);
            float rc0 = r4.x - v0, rc1 = r4.y - v1;
            float rc2 = r4.z - v2, rc3 = r4.w - v3;
            float l1 = rc0; int s1 = 0;
            if (rc1 < l1) { l1 = rc1; s1 = 1; }
            if (rc2 < l1) { l1 = rc2; s1 = 2; }
            if (rc3 < l1) { l1 = rc3; s1 = 3; }
            float l2 = FINF;
            if (s1 != 0) l2 = fminf(l2, rc0);
            if (s1 != 1) l2 = fminf(l2, rc1);
            if (s1 != 2) l2 = fminf(l2, rc2);
            if (s1 != 3) l2 = fminf(l2, rc3);

            float g1 = l1, g2 = l2;
            DPP_PAIR_STAGE(g1, g2, 0x111);   // row_shr:1
            DPP_PAIR_STAGE(g1, g2, 0x112);   // row_shr:2
            DPP_PAIR_STAGE(g1, g2, 0x114);   // row_shr:4
            DPP_PAIR_STAGE(g1, g2, 0x118);   // row_shr:8
            DPP_PAIR_STAGE(g1, g2, 0x142);   // row_bcast:15
            DPP_PAIR_STAGE(g1, g2, 0x143);   // row_bcast:31
            float u1 = __int_as_float(
                __builtin_amdgcn_readlane(__float_as_int(g1), 63));
            float u2 = __int_as_float(
                __builtin_amdgcn_readlane(__float_as_int(g2), 63));
            unsigned long long ball = __ballot(l1 == u1);
            int owner = __builtin_ctzll(ball);
            int pk = (j_base + s1) | (sel4(p0, p1, p2, p3, s1) << 9);
            pk = __builtin_amdgcn_readlane(pk, owner);
            int j1 = pk & 511, k = pk >> 9;

            if (u1 < u2) {
                // take j1: u[i]=u2, v[j1] -= (u2-u1) -> rc[i][j1]=0 exact
                if (lane == 0) u[i] = u2;
                if (lane == ((j1 - 1) >> 2)) {
                    int s = (j1 - 1) & 3;
                    float dv = u2 - u1;
                    if (s == 0) { v0 -= dv; p0 = i; }
                    else if (s == 1) { v1 -= dv; p1 = i; }
                    else if (s == 2) { v2 -= dv; p2 = i; }
                    else { v3 -= dv; p3 = i; }
                }
                if (k > 0) { i = k; continue; }   // displaced row continues
            } else if (k == 0) {
                // exact tie but column free: assign, no v change
                if (lane == 0) u[i] = u1;
                if (lane == ((j1 - 1) >> 2)) {
                    int s = (j1 - 1) & 3;
                    if (s == 0) p0 = i;
                    else if (s == 1) p1 = i;
                    else if (s == 2) p2 = i;
                    else p3 = i;
                }
            } else {
                // exact tie on occupied column: defer to Dijkstra (u=min1
                // keeps rc >= 0 with equality at j1 -> feasible)
                if (lane == 0) { u[i] = u1; dlist[dcnt] = i; }
                dcnt++;
            }
            i = (pi < ucnt) ? ulist[pi++] : 0;
        }
    }
    __syncthreads();

    // ---- stage 3: Dijkstra phases for deferred targets ----
    for (int uk = 0; uk < dcnt; ++uk) {
        int t = dlist[uk];
        m0 = FINF; m1 = FINF; m2 = FINF; m3 = FINF;
        int usedm = 0;
        float ur0 = 0, ur1 = 0, ur2 = 0, ur3 = 0;   // u of tree row per slot
        int tg0 = 0, tg1 = 0, tg2 = 0, tg3 = 0;     // tree-row target per slot
        int j0 = 0;                 // current pred-col (0 = virtual)
        int icur = t;               // row being scanned (p[j0]; p[0] = t)
        float ut = u[t];            // u[t], tracked in-register (wave-uniform)
        float u0 = ut;
        float4 r4 = *reinterpret_cast<const float4*>(
            C + (size_t)(t - 1) * M + 4 * lane);
        int jn;

        while (true) {
            // used[j0] = True; seed register copy of u[p[j0]]
            if (j0 != 0 && ((j0 - 1) >> 2) == lane) {
                int s = (j0 - 1) & 3;
                usedm |= 1 << s;
                if (s == 0) { ur0 = u0; tg0 = icur; }
                else if (s == 1) { ur1 = u0; tg1 = icur; }
                else if (s == 2) { ur2 = u0; tg2 = icur; }
                else { ur3 = u0; tg3 = icur; }
            }

            // cur = (c - u) - v ; strict < update (free cols only)
            float a0 = FINF, a1 = FINF, a2f = FINF, a3 = FINF;
            if (!(usedm & 1)) {
                float cur = (r4.x - u0) - v0;
                if (cur < m0) { m0 = cur; w0 = j0; }
                a0 = m0;
            }
            if (!(usedm & 2)) {
                float cur = (r4.y - u0) - v1;
                if (cur < m1) { m1 = cur; w1 = j0; }
                a1 = m1;
            }
            if (!(usedm & 4)) {
                float cur = (r4.z - u0) - v2;
                if (cur < m2) { m2 = cur; w2 = j0; }
                a2f = m2;
            }
            if (!(usedm & 8)) {
                float cur = (r4.w - u0) - v3;
                if (cur < m3) { m3 = cur; w3 = j0; }
                a3 = m3;
            }

            // lane-local (min, smallest slot)
            float av = a0; int sa = 0;
            if (a1 < av)  { av = a1;  sa = 1; }
            if (a2f < av) { av = a2f; sa = 2; }
            if (a3 < av)  { av = a3;  sa = 3; }

            // wave min via v_min_f32 DPP ladder; lane 63 holds the result
            float wv_ = av;
            DPP_FMIN32_STAGE(wv_, 0x111);   // row_shr:1
            DPP_FMIN32_STAGE(wv_, 0x112);   // row_shr:2
            DPP_FMIN32_STAGE(wv_, 0x114);   // row_shr:4
            DPP_FMIN32_STAGE(wv_, 0x118);   // row_shr:8
            DPP_FMIN32_STAGE(wv_, 0x142);   // row_bcast:15
            DPP_FMIN32_STAGE(wv_, 0x143);   // row_bcast:31
            float delta = __int_as_float(
                __builtin_amdgcn_readlane(__float_as_int(wv_), 63));

            unsigned long long ball = __ballot(av == delta);
            int owner = __builtin_ctzll(ball);   // lowest lane = smallest col
            int pk = (j_base + sa) | (sel4(p0, p1, p2, p3, sa) << 9);
            pk = __builtin_amdgcn_readlane(pk, owner);
            int jn_ = pk & 511, pjn = pk >> 9;

            // early reads for next iteration (u has NO writes during a phase)
            int nxt = (pjn > 0) ? pjn : t;
            float u_next = u[nxt];
            float4 r4n = *reinterpret_cast<const float4*>(
                C + (size_t)(nxt - 1) * M + 4 * lane);

            // per-iteration dual/minv updates (register-resident)
            if (usedm & 1) { ur0 += delta; v0 -= delta; } else m0 -= delta;
            if (usedm & 2) { ur1 += delta; v1 -= delta; } else m1 -= delta;
            if (usedm & 4) { ur2 += delta; v2 -= delta; } else m2 -= delta;
            if (usedm & 8) { ur3 += delta; v3 -= delta; } else m3 -= delta;
            ut += delta;                       // virtual column: p[0] = t

            jn = jn_;
            if (pjn == 0) break;
            j0 = jn_; u0 = u_next; r4 = r4n; icur = pjn;
        }

        // phase-end u writeback (distinct targets per used column: race-free)
        if (usedm & 1) u[tg0] = ur0;
        if (usedm & 2) u[tg1] = ur1;
        if (usedm & 4) u[tg2] = ur2;
        if (usedm & 8) u[tg3] = ur3;
        if (lane == 0) u[t] = ut;

        // augment: stream p[j_k] = p_old[j_{k+1}] one step behind the
        // traversal; one readlane per step (packed way|p).
        int jj = jn, prev = 0;
        while (true) {
            int idx = jj - 1;
            int o = idx >> 2, s = idx & 3;
            int packv = sel4(w0, w1, w2, w3, s) |
                        (sel4(p0, p1, p2, p3, s) << 9);
            packv = __builtin_amdgcn_readlane(packv, o);
            int wv = packv & 511, pold = packv >> 9;
            if (prev != 0) {
                int pi = prev - 1;
                if (lane == (pi >> 2)) {
                    int sp = pi & 3;
                    if (sp == 0) p0 = pold;
                    else if (sp == 1) p1 = pold;
                    else if (sp == 2) p2 = pold;
                    else p3 = pold;
                }
            }
            if (wv == 0) {
                if (lane == o) {
                    if (s == 0) p0 = t;
                    else if (s == 1) p1 = t;
                    else if (s == 2) p2 = t;
                    else p3 = t;
                }
                break;
            }
            prev = jj; jj = wv;
        }
    }

    // matched sums over real pairs: pred-col j (owned) matched to target p[j]
    double sm = 0.0, ss = 0.0, sb = 0.0;
#pragma unroll
    for (int s = 0; s < 4; ++s) {
        int pt = sel4(p0, p1, p2, p3, s);
        if (pt != 0) {
            int r = j_base + s - 1;   // pred index
            int c = pt - 1;           // target index
            sm += (double)C[(size_t)c * M + r];
            sb += (double)boxc[((size_t)b * M + r) * N + c];
            ss += (double)fmaxf(0.0f, t_score[b * N + c] - p_score[b * M + r]);
        }
    }
#pragma unroll
    for (int off = 1; off < 64; off <<= 1) {
        sm += __shfl_xor(sm, off, 64);
        ss += __shfl_xor(ss, off, 64);
        sb += __shfl_xor(sb, off, 64);
    }
    if (lane == 0) {
        out[0 * B + b] = (float)(sm / N);
        out[1 * B + b] = (float)(ss / N);
        out[2 * B + b] = (float)(sb / N);
    }
}

extern "C" void kernel_launch(void* const* d_in, const int* in_sizes, int n_in,
                              void* d_out, int out_size, void* d_ws, size_t ws_size,
                              hipStream_t stream) {
    int B = out_size / 3;                 // out is [3, B]
    int M = in_sizes[1] / B;              // pred_score [B, M]
    int N = in_sizes[3] / B;              // target_score [B, N]

    const float* p_box   = (const float*)d_in[0];
    const float* p_score = (const float*)d_in[1];
    const float* t_box   = (const float*)d_in[2];
    const float* t_score = (const float*)d_in[3];
    float* out = (float*)d_out;

    float* Ct   = (float*)d_ws;                       // [B, N, M]
    float* boxc = Ct + (size_t)B * N * M;             // [B, M, N]
    float* rmv  = boxc + (size_t)B * M * N;           // [B, N]
    int*   rmj  = (int*)(rmv + (size_t)B * N);        // [B, N]

    int total = B * M * N;
    cost_kernel<<<(total + 255) / 256, 256, 0, stream>>>(
        p_box, p_score, t_box, t_score, Ct, boxc, B, M, N);
    rowmin_kernel<<<B * N, 64, 0, stream>>>(Ct, rmv, rmj, M);
    hungarian_rect<<<B, 64, 0, stream>>>(
        Ct, boxc, p_score, t_score, rmv, rmj, out, B, M, N);
}

// Round 9
// 230.220 us; speedup vs baseline: 91.5558x; 2.5230x over previous
//
#include <hip/hip_runtime.h>
#include <cmath>

#define MAXV 8

// ---------------------------------------------------------------------------
// Kernel 1: cost matrices for the RECTANGULAR problem (no padding).
// One thread per (b, n, m), m fastest. Writes:
//   Ct[b][n][m]  = score_cost + giou_cost   (transposed cost, coalesced rows)
//   boxc[b][m][n] = giou_cost
// Math mirrors the reference f32 op order exactly.
// ---------------------------------------------------------------------------
__global__ __launch_bounds__(256) void cost_kernel(
    const float* __restrict__ p_box, const float* __restrict__ p_score,
    const float* __restrict__ t_box, const float* __restrict__ t_score,
    float* __restrict__ Ct, float* __restrict__ boxc,
    int B, int M, int N)
{
    int g = blockIdx.x * 256 + threadIdx.x;
    int total = B * M * N;
    if (g >= total) return;
    int b = g / (M * N);
    int rem = g - b * M * N;
    int n = rem / M;
    int m = rem - n * M;

    const float* bp = p_box + ((size_t)b * M + m) * 5;
    const float* bt = t_box + ((size_t)b * N + n) * 5;
    float pcx = bp[0], pcy = bp[1], pw = bp[2], ph = bp[3], pth = bp[4];
    float tcx = bt[0], tcy = bt[1], tw = bt[2], th = bt[3], tth = bt[4];

    float pc = cosf(pth), ps = sinf(pth);
    float tc = cosf(tth), ts = sinf(tth);

    const float DX[4] = {-0.5f, 0.5f, 0.5f, -0.5f};
    const float DY[4] = {-0.5f, -0.5f, 0.5f, 0.5f};
    float cpx[4], cpy[4], ctx[4], cty[4];
#pragma unroll
    for (int k = 0; k < 4; k++) {
        float dx = DX[k] * pw, dy = DY[k] * ph;
        cpx[k] = pcx + dx * pc - dy * ps;
        cpy[k] = pcy + dx * ps + dy * pc;
        float dx2 = DX[k] * tw, dy2 = DY[k] * th;
        ctx[k] = tcx + dx2 * tc - dy2 * ts;
        cty[k] = tcy + dx2 * ts + dy2 * tc;
    }

    float px[MAXV], py[MAXV];
#pragma unroll
    for (int k = 0; k < MAXV; k++) {
        px[k] = (k < 4) ? cpx[k] : 0.0f;
        py[k] = (k < 4) ? cpy[k] : 0.0f;
    }
    int cnt = 4;

#pragma unroll
    for (int e = 0; e < 4; e++) {
        float ax = ctx[e], ay = cty[e];
        float bx2 = ctx[(e + 1) & 3], by2 = cty[(e + 1) & 3];
        float dx = bx2 - ax, dy = by2 - ay;
        float qx[MAXV], qy[MAXV];
#pragma unroll
        for (int k = 0; k < MAXV; k++) { qx[k] = 0.0f; qy[k] = 0.0f; }
        int nc = 0;
#pragma unroll
        for (int i = 0; i < MAXV; i++) {
            if (i < cnt) {
                bool wrap = !(i + 1 < cnt);
                float nx = wrap ? px[0] : px[(i + 1) & 7];
                float ny = wrap ? py[0] : py[(i + 1) & 7];
                float sc = dx * (py[i] - ay) - dy * (px[i] - ax);
                float sn = dx * (ny - ay) - dy * (nx - ax);
                bool inc = (sc >= 0.0f), inn = (sn >= 0.0f);
                float den = sc - sn;
                if (!(fabsf(den) > 1e-9f)) den = 1e-9f;
                float t = sc / den;
                float ix = px[i] + t * (nx - px[i]);
                float iy = py[i] + t * (ny - py[i]);
                if (inc) {
                    if (nc < MAXV) { qx[nc] = px[i]; qy[nc] = py[i]; }
                    nc++;
                }
                if (inc != inn) {
                    if (nc < MAXV) { qx[nc] = ix; qy[nc] = iy; }
                    nc++;
                }
            }
        }
        cnt = (nc > MAXV) ? MAXV : nc;
#pragma unroll
        for (int k = 0; k < MAXV; k++) {
            px[k] = (k < cnt) ? qx[k] : 0.0f;
            py[k] = (k < cnt) ? qy[k] : 0.0f;
        }
    }

    float a2 = 0.0f;
#pragma unroll
    for (int i = 0; i < MAXV; i++) {
        if (i < cnt) {
            bool wrap = !(i + 1 < cnt);
            float nx = wrap ? px[0] : px[(i + 1) & 7];
            float ny = wrap ? py[0] : py[(i + 1) & 7];
            a2 += px[i] * ny - nx * py[i];
        }
    }
    float inter = 0.5f * fabsf(a2);

    float uni = tw * th + pw * ph - inter;

    float xmin = ctx[0], xmax = ctx[0], ymin = cty[0], ymax = cty[0];
#pragma unroll
    for (int k = 1; k < 4; k++) {
        xmin = fminf(xmin, ctx[k]); xmax = fmaxf(xmax, ctx[k]);
        ymin = fminf(ymin, cty[k]); ymax = fmaxf(ymax, cty[k]);
    }
#pragma unroll
    for (int k = 0; k < 4; k++) {
        xmin = fminf(xmin, cpx[k]); xmax = fmaxf(xmax, cpx[k]);
        ymin = fminf(ymin, cpy[k]); ymax = fmaxf(ymax, cpy[k]);
    }
    float enc = (xmax - xmin) * (ymax - ymin);

    float giou = inter / uni - (enc - uni) / enc;
    float bc = 1.0f - giou;
    float scst = fmaxf(0.0f, t_score[b * N + n] - p_score[b * M + m]);

    Ct[((size_t)b * N + n) * M + m] = scst + bc;
    boxc[((size_t)b * M + m) * N + n] = bc;
}

// ---------------------------------------------------------------------------
// Kernel 1.5: per-target-row min over the M pred columns (u init).
// ---------------------------------------------------------------------------
__global__ __launch_bounds__(64) void rowmin_kernel(
    const float* __restrict__ Ct, float* __restrict__ rmv, int M)
{
    int bt = blockIdx.x;
    int lane = threadIdx.x;
    const float* row = Ct + (size_t)bt * M;

    float bv = 1e30f;
    for (int c = 4 * lane; c < M; c += 256) {
        float4 v = *reinterpret_cast<const float4*>(row + c);
        bv = fminf(bv, fminf(fminf(v.x, v.y), fminf(v.z, v.w)));
    }
#pragma unroll
    for (int off = 1; off < 64; off <<= 1)
        bv = fminf(bv, __shfl_xor(bv, off, 64));
    if (lane == 0) rmv[bt] = bv;
}

// ---------------------------------------------------------------------------
// Kernel 1.6: per-column (min, first argmin row) of the u-reduced matrix:
//   vmin[b][j] = min_t (Ct[b][t][j] - rmv[b][t]),  varg = argmin t (1-based).
// This builds the v duals IN PARALLEL (1024 independent reductions) instead
// of letting the serial solver wave accrete them one delta at a time.
// ---------------------------------------------------------------------------
__global__ __launch_bounds__(256) void colmin_kernel(
    const float* __restrict__ Ct, const float* __restrict__ rmv,
    float* __restrict__ vmin, int* __restrict__ varg, int M, int N)
{
    int b = blockIdx.x;
    const float* Cb = Ct + (size_t)b * N * M;
    const float* rb = rmv + (size_t)b * N;
    for (int j = threadIdx.x; j < M; j += blockDim.x) {
        float bv = 1e30f; int bt = 0;
        for (int t = 0; t < N; ++t) {
            float val = Cb[(size_t)t * M + j] - rb[t];
            if (val < bv) { bv = val; bt = t; }
        }
        vmin[(size_t)b * M + j] = bv;
        varg[(size_t)b * M + j] = bt + 1;   // 1-based target
    }
}

// ---------------------------------------------------------------------------
// Kernel 2: rectangular JV Hungarian, single wave per batch, four stages:
//  (1) two-sided-reduction init: u[t]=rowmin, v[j]=colmin of reduced matrix
//      (both computed by parallel kernels); column-side greedy: col j claims
//      its argmin row (rc==0 exactly in f32), conflicts -> smallest j via
//      LDS atomicMin. CS + feasibility hold exactly.
//  (2) augmenting row reduction (exact JV ARR) for leftover rows.
//  (3) e-maxx Dijkstra phases for ARR-deferred rows.
//  (4) matched sums.
// Stages 2/3 are unchanged from round 8 (proven correct); they just start
// from globally-informed duals so chains/paths are much shorter.
// ---------------------------------------------------------------------------
__device__ __forceinline__ int sel4(int a0, int a1, int a2, int a3, int s) {
    return s == 0 ? a0 : (s == 1 ? a1 : (s == 2 ? a2 : a3));
}

// val = fminf(val, dpp_neighbor(val)); invalid lanes contribute +inf.
#define DPP_FMIN32_STAGE(val, CTRL) do {                                      \
    int _o = __builtin_amdgcn_update_dpp(0x7F800000,                          \
                 __float_as_int(val), CTRL, 0xf, 0xf, false);                 \
    (val) = fminf((val), __int_as_float(_o));                                 \
} while (0)

// paired (min1,min2) reduction stage; disjoint lane-set combine.
#define DPP_PAIR_STAGE(g1, g2, CTRL) do {                                     \
    int _b1 = __builtin_amdgcn_update_dpp(0x7F800000,                         \
                  __float_as_int(g1), CTRL, 0xf, 0xf, false);                 \
    int _b2 = __builtin_amdgcn_update_dpp(0x7F800000,                         \
                  __float_as_int(g2), CTRL, 0xf, 0xf, false);                 \
    float _o1 = __int_as_float(_b1), _o2 = __int_as_float(_b2);               \
    float _n2 = fminf(fmaxf((g1), _o1), fminf((g2), _o2));                    \
    (g1) = fminf((g1), _o1);                                                  \
    (g2) = _n2;                                                               \
} while (0)

__global__ __launch_bounds__(64) void hungarian_rect(
    const float* __restrict__ Ct, const float* __restrict__ boxc,
    const float* __restrict__ p_score, const float* __restrict__ t_score,
    const float* __restrict__ rmv, const float* __restrict__ vmin,
    const int* __restrict__ varg,
    float* __restrict__ out, int B, int M, int N)
{
    const float FINF = 1e30f;
    const int IINF = 0x7fffffff;
    int b = blockIdx.x;
    int lane = threadIdx.x;
    const float* C = Ct + (size_t)b * N * M;   // [N][M] rows contiguous

    __shared__ float u[257];                   // indexed by target 1..N
    __shared__ int claim[257];                 // row -> smallest claiming col
    __shared__ int ulist[257];                 // rows for ARR
    __shared__ int dlist[257];                 // rows for Dijkstra

    // ---- warm local-XCD L2 with this batch's cost rows (~192 KB) ----
    {
        int total = N * M;
        for (int off = 4 * lane; off < total; off += 256) {
            float4 w = *reinterpret_cast<const float4*>(C + off);
            asm volatile("" :: "v"(w.x), "v"(w.y), "v"(w.z), "v"(w.w));
        }
    }

    for (int k = lane; k < N; k += 64) u[k + 1] = rmv[b * N + k];
    for (int k = lane; k < 257; k += 64) claim[k] = IINF;
    __syncthreads();

    const int j_base = 4 * lane + 1;           // first owned pred-col (1-based)
    // v duals from colmin kernel
    float v0, v1, v2, v3;
    int va0, va1, va2, va3;
    {
        const float4 vm = *reinterpret_cast<const float4*>(
            vmin + (size_t)b * M + 4 * lane);
        v0 = vm.x; v1 = vm.y; v2 = vm.z; v3 = vm.w;
        const int4 vg = *reinterpret_cast<const int4*>(
            varg + (size_t)b * M + 4 * lane);
        va0 = vg.x; va1 = vg.y; va2 = vg.z; va3 = vg.w;
    }

    float m0, m1, m2, m3;
    int p0 = 0, p1 = 0, p2 = 0, p3 = 0;        // pred-col -> matched target
    int w0 = 0, w1 = 0, w2 = 0, w3 = 0;

    // ---- stage 1: column-side greedy via claims (rc==0 pairs exactly) ----
    atomicMin(&claim[va0], j_base + 0);
    atomicMin(&claim[va1], j_base + 1);
    atomicMin(&claim[va2], j_base + 2);
    atomicMin(&claim[va3], j_base + 3);
    __syncthreads();
    p0 = (claim[va0] == j_base + 0) ? va0 : 0;
    p1 = (claim[va1] == j_base + 1) ? va1 : 0;
    p2 = (claim[va2] == j_base + 2) ? va2 : 0;
    p3 = (claim[va3] == j_base + 3) ? va3 : 0;

    // unmatched-row list (ascending), ballot compaction
    int ucnt = 0;
    for (int c0 = 0; c0 < N; c0 += 64) {
        int t = c0 + lane + 1;
        bool un = (t <= N) && (claim[t] == IINF);
        unsigned long long mask = __ballot(un);
        int pos = ucnt + __popcll(mask & ((1ULL << lane) - 1ULL));
        if (un) ulist[pos] = t;
        ucnt += (int)__popcll(mask);
    }
    __syncthreads();

    // ---- stage 2: augmenting row reduction (exact JV ARR) ----
    int dcnt = 0;
    {
        int pi = 0, steps = 0;
        int i = (pi < ucnt) ? ulist[pi++] : 0;
        while (i != 0) {
            ++steps;
            if (steps > 2048) {          // safety cap: dump rest to Dijkstra
                if (lane == 0) dlist[dcnt] = i;
                dcnt++;
                while (pi < ucnt) {
                    if (lane == 0) dlist[dcnt] = ulist[pi];
                    dcnt++; pi++;
                }
                break;
            }
            float4 r4 = *reinterpret_cast<const float4*>(
                C + (size_t)(i - 1) * M + 4 * lane);
            float rc0 = r4.x - v0, rc1 = r4.y - v1;
            float rc2 = r4.z - v2, rc3 = r4.w - v3;
            float l1 = rc0; int s1 = 0;
            if (rc1 < l1) { l1 = rc1; s1 = 1; }
            if (rc2 < l1) { l1 = rc2; s1 = 2; }
            if (rc3 < l1) { l1 = rc3; s1 = 3; }
            float l2 = FINF;
            if (s1 != 0) l2 = fminf(l2, rc0);
            if (s1 != 1) l2 = fminf(l2, rc1);
            if (s1 != 2) l2 = fminf(l2, rc2);
            if (s1 != 3) l2 = fminf(l2, rc3);

            float g1 = l1, g2 = l2;
            DPP_PAIR_STAGE(g1, g2, 0x111);   // row_shr:1
            DPP_PAIR_STAGE(g1, g2, 0x112);   // row_shr:2
            DPP_PAIR_STAGE(g1, g2, 0x114);   // row_shr:4
            DPP_PAIR_STAGE(g1, g2, 0x118);   // row_shr:8
            DPP_PAIR_STAGE(g1, g2, 0x142);   // row_bcast:15
            DPP_PAIR_STAGE(g1, g2, 0x143);   // row_bcast:31
            float u1 = __int_as_float(
                __builtin_amdgcn_readlane(__float_as_int(g1), 63));
            float u2 = __int_as_float(
                __builtin_amdgcn_readlane(__float_as_int(g2), 63));
            unsigned long long ball = __ballot(l1 == u1);
            int owner = __builtin_ctzll(ball);
            int pk = (j_base + s1) | (sel4(p0, p1, p2, p3, s1) << 9);
            pk = __builtin_amdgcn_readlane(pk, owner);
            int j1 = pk & 511, k = pk >> 9;

            if (u1 < u2) {
                // take j1: u[i]=u2, v[j1] -= (u2-u1) -> rc[i][j1]=0 exact
                if (lane == 0) u[i] = u2;
                if (lane == ((j1 - 1) >> 2)) {
                    int s = (j1 - 1) & 3;
                    float dv = u2 - u1;
                    if (s == 0) { v0 -= dv; p0 = i; }
                    else if (s == 1) { v1 -= dv; p1 = i; }
                    else if (s == 2) { v2 -= dv; p2 = i; }
                    else { v3 -= dv; p3 = i; }
                }
                if (k > 0) { i = k; continue; }   // displaced row continues
            } else if (k == 0) {
                // exact tie but column free: assign, no v change
                if (lane == 0) u[i] = u1;
                if (lane == ((j1 - 1) >> 2)) {
                    int s = (j1 - 1) & 3;
                    if (s == 0) p0 = i;
                    else if (s == 1) p1 = i;
                    else if (s == 2) p2 = i;
                    else p3 = i;
                }
            } else {
                // exact tie on occupied column: defer to Dijkstra
                if (lane == 0) { u[i] = u1; dlist[dcnt] = i; }
                dcnt++;
            }
            i = (pi < ucnt) ? ulist[pi++] : 0;
        }
    }
    __syncthreads();

    // ---- stage 3: Dijkstra phases for deferred targets ----
    for (int uk = 0; uk < dcnt; ++uk) {
        int t = dlist[uk];
        m0 = FINF; m1 = FINF; m2 = FINF; m3 = FINF;
        int usedm = 0;
        float ur0 = 0, ur1 = 0, ur2 = 0, ur3 = 0;   // u of tree row per slot
        int tg0 = 0, tg1 = 0, tg2 = 0, tg3 = 0;     // tree-row target per slot
        int j0 = 0;                 // current pred-col (0 = virtual)
        int icur = t;               // row being scanned (p[j0]; p[0] = t)
        float ut = u[t];            // u[t], tracked in-register (wave-uniform)
        float u0 = ut;
        float4 r4 = *reinterpret_cast<const float4*>(
            C + (size_t)(t - 1) * M + 4 * lane);
        int jn;

        while (true) {
            // used[j0] = True; seed register copy of u[p[j0]]
            if (j0 != 0 && ((j0 - 1) >> 2) == lane) {
                int s = (j0 - 1) & 3;
                usedm |= 1 << s;
                if (s == 0) { ur0 = u0; tg0 = icur; }
                else if (s == 1) { ur1 = u0; tg1 = icur; }
                else if (s == 2) { ur2 = u0; tg2 = icur; }
                else { ur3 = u0; tg3 = icur; }
            }

            // cur = (c - u) - v ; strict < update (free cols only)
            float a0 = FINF, a1 = FINF, a2f = FINF, a3 = FINF;
            if (!(usedm & 1)) {
                float cur = (r4.x - u0) - v0;
                if (cur < m0) { m0 = cur; w0 = j0; }
                a0 = m0;
            }
            if (!(usedm & 2)) {
                float cur = (r4.y - u0) - v1;
                if (cur < m1) { m1 = cur; w1 = j0; }
                a1 = m1;
            }
            if (!(usedm & 4)) {
                float cur = (r4.z - u0) - v2;
                if (cur < m2) { m2 = cur; w2 = j0; }
                a2f = m2;
            }
            if (!(usedm & 8)) {
                float cur = (r4.w - u0) - v3;
                if (cur < m3) { m3 = cur; w3 = j0; }
                a3 = m3;
            }

            // lane-local (min, smallest slot)
            float av = a0; int sa = 0;
            if (a1 < av)  { av = a1;  sa = 1; }
            if (a2f < av) { av = a2f; sa = 2; }
            if (a3 < av)  { av = a3;  sa = 3; }

            // wave min via v_min_f32 DPP ladder; lane 63 holds the result
            float wv_ = av;
            DPP_FMIN32_STAGE(wv_, 0x111);   // row_shr:1
            DPP_FMIN32_STAGE(wv_, 0x112);   // row_shr:2
            DPP_FMIN32_STAGE(wv_, 0x114);   // row_shr:4
            DPP_FMIN32_STAGE(wv_, 0x118);   // row_shr:8
            DPP_FMIN32_STAGE(wv_, 0x142);   // row_bcast:15
            DPP_FMIN32_STAGE(wv_, 0x143);   // row_bcast:31
            float delta = __int_as_float(
                __builtin_amdgcn_readlane(__float_as_int(wv_), 63));

            unsigned long long ball = __ballot(av == delta);
            int owner = __builtin_ctzll(ball);   // lowest lane = smallest col
            int pk = (j_base + sa) | (sel4(p0, p1, p2, p3, sa) << 9);
            pk = __builtin_amdgcn_readlane(pk, owner);
            int jn_ = pk & 511, pjn = pk >> 9;

            // early reads for next iteration (u has NO writes during a phase)
            int nxt = (pjn > 0) ? pjn : t;
            float u_next = u[nxt];
            float4 r4n = *reinterpret_cast<const float4*>(
                C + (size_t)(nxt - 1) * M + 4 * lane);

            // per-iteration dual/minv updates (register-resident)
            if (usedm & 1) { ur0 += delta; v0 -= delta; } else m0 -= delta;
            if (usedm & 2) { ur1 += delta; v1 -= delta; } else m1 -= delta;
            if (usedm & 4) { ur2 += delta; v2 -= delta; } else m2 -= delta;
            if (usedm & 8) { ur3 += delta; v3 -= delta; } else m3 -= delta;
            ut += delta;                       // virtual column: p[0] = t

            jn = jn_;
            if (pjn == 0) break;
            j0 = jn_; u0 = u_next; r4 = r4n; icur = pjn;
        }

        // phase-end u writeback (distinct targets per used column: race-free)
        if (usedm & 1) u[tg0] = ur0;
        if (usedm & 2) u[tg1] = ur1;
        if (usedm & 4) u[tg2] = ur2;
        if (usedm & 8) u[tg3] = ur3;
        if (lane == 0) u[t] = ut;

        // augment: stream p[j_k] = p_old[j_{k+1}] one step behind the
        // traversal; one readlane per step (packed way|p).
        int jj = jn, prev = 0;
        while (true) {
            int idx = jj - 1;
            int o = idx >> 2, s = idx & 3;
            int packv = sel4(w0, w1, w2, w3, s) |
                        (sel4(p0, p1, p2, p3, s) << 9);
            packv = __builtin_amdgcn_readlane(packv, o);
            int wv = packv & 511, pold = packv >> 9;
            if (prev != 0) {
                int pi = prev - 1;
                if (lane == (pi >> 2)) {
                    int sp = pi & 3;
                    if (sp == 0) p0 = pold;
                    else if (sp == 1) p1 = pold;
                    else if (sp == 2) p2 = pold;
                    else p3 = pold;
                }
            }
            if (wv == 0) {
                if (lane == o) {
                    if (s == 0) p0 = t;
                    else if (s == 1) p1 = t;
                    else if (s == 2) p2 = t;
                    else p3 = t;
                }
                break;
            }
            prev = jj; jj = wv;
        }
    }

    // matched sums over real pairs: pred-col j (owned) matched to target p[j]
    double sm = 0.0, ss = 0.0, sb = 0.0;
#pragma unroll
    for (int s = 0; s < 4; ++s) {
        int pt = sel4(p0, p1, p2, p3, s);
        if (pt != 0) {
            int r = j_base + s - 1;   // pred index
            int c = pt - 1;           // target index
            sm += (double)C[(size_t)c * M + r];
            sb += (double)boxc[((size_t)b * M + r) * N + c];
            ss += (double)fmaxf(0.0f, t_score[b * N + c] - p_score[b * M + r]);
        }
    }
#pragma unroll
    for (int off = 1; off < 64; off <<= 1) {
        sm += __shfl_xor(sm, off, 64);
        ss += __shfl_xor(ss, off, 64);
        sb += __shfl_xor(sb, off, 64);
    }
    if (lane == 0) {
        out[0 * B + b] = (float)(sm / N);
        out[1 * B + b] = (float)(ss / N);
        out[2 * B + b] = (float)(sb / N);
    }
}

extern "C" void kernel_launch(void* const* d_in, const int* in_sizes, int n_in,
                              void* d_out, int out_size, void* d_ws, size_t ws_size,
                              hipStream_t stream) {
    int B = out_size / 3;                 // out is [3, B]
    int M = in_sizes[1] / B;              // pred_score [B, M]
    int N = in_sizes[3] / B;              // target_score [B, N]

    const float* p_box   = (const float*)d_in[0];
    const float* p_score = (const float*)d_in[1];
    const float* t_box   = (const float*)d_in[2];
    const float* t_score = (const float*)d_in[3];
    float* out = (float*)d_out;

    float* Ct   = (float*)d_ws;                       // [B, N, M]
    float* boxc = Ct + (size_t)B * N * M;             // [B, M, N]
    float* rmv  = boxc + (size_t)B * M * N;           // [B, N]
    float* vmin = rmv + (size_t)B * N;                // [B, M]
    int*   varg = (int*)(vmin + (size_t)B * M);       // [B, M]

    int total = B * M * N;
    cost_kernel<<<(total + 255) / 256, 256, 0, stream>>>(
        p_box, p_score, t_box, t_score, Ct, boxc, B, M, N);
    rowmin_kernel<<<B * N, 64, 0, stream>>>(Ct, rmv, M);
    colmin_kernel<<<B, 256, 0, stream>>>(Ct, rmv, vmin, varg, M, N);
    hungarian_rect<<<B, 64, 0, stream>>>(
        Ct, boxc, p_score, t_score, rmv, vmin, varg, out, B, M, N);
}